// Round 1
// baseline (323.842 us; speedup 1.0000x reference)
//
#include <hip/hip_runtime.h>
#include <math.h>

// Problem constants (fixed by setup_inputs)
#define NROWS 32768   // 32 * 32 * 32
#define DIMS  256
#define KCODES 1024

typedef __attribute__((ext_vector_type(8))) short short8;   // 8 bf16 = 4 VGPRs
typedef __attribute__((ext_vector_type(4))) float f32x4;    // MFMA C/D & NT stores

// ws layout (float offsets) — flat region retained but unused now
static const size_t OFF_WB     = 8388608;                // [1024][256] bf16, MFMA-fragment tile order
static const size_t OFF_WNORM  = OFF_WB + 131072;        // [1024]
static const size_t OFF_ENCSUM = OFF_WNORM + 1024;       // [1024]
static const size_t OFF_LOSSP  = OFF_ENCSUM + 1024;      // [512 used]
static const size_t OFF_I0     = OFF_LOSSP + 8192;       // [32768] int
static const size_t OFF_I1     = OFF_I0 + 32768;         // [32768] int
static const size_t OFF_W0     = OFF_I1 + 32768;         // [32768] float
static const size_t OFF_W1     = OFF_W0 + 32768;         // [32768] float

// out layout (float offsets): loss | quantized NCHW | perplexity | encodings
static const size_t OUT_Q    = 1;
static const size_t OUT_PERP = 8388609;
static const size_t OUT_ENC  = 8388610;

__device__ inline unsigned short f2bf(float f) {
    unsigned int u = __float_as_uint(f);
    unsigned int r = u + 0x7FFFu + ((u >> 16) & 1u);   // RNE
    return (unsigned short)(r >> 16);
}

// pack distance (fp32, low 10 mantissa bits cleared) with 10-bit code index.
__device__ inline float packdi(float d, int code) {
    return __uint_as_float((__float_as_uint(d) & 0xFFFFFC00u) | (unsigned)code);
}

// async global->LDS copy, 16B per lane (wave-uniform LDS base + lane*16)
__device__ __forceinline__ void gl_lds16(const void* gsrc, void* ldst) {
    typedef const __attribute__((address_space(1))) unsigned int GU;
    typedef __attribute__((address_space(3))) unsigned int LU;
    __builtin_amdgcn_global_load_lds((GU*)gsrc, (LU*)ldst, 16, 0, 0);
}

// ---------------- W prep: bf16 fragment-order layout + wnorm + zero enc_sum ----
// Tile tt = code>>4 (16 codes). Element (code, dim): col=code&15, kk=dim>>5,
// quad=(dim>>3)&3, j=dim&7 at tt*4096 + ((kk*4+quad)*16 + col)*8 + j.
__global__ __launch_bounds__(256) void wprep(const float* __restrict__ Wm,
                                             unsigned short* __restrict__ Wb,
                                             float* __restrict__ wnorm,
                                             float* __restrict__ enc_sum)
{
    const int r = blockIdx.x * 4 + (threadIdx.x >> 6);
    const int lane = threadIdx.x & 63;
    float4 v = ((const float4*)(Wm + (size_t)r * 256))[lane];
    ushort4 o;
    o.x = f2bf(v.x); o.y = f2bf(v.y); o.z = f2bf(v.z); o.w = f2bf(v.w);
    const int d0 = lane * 4;
    const int kk = d0 >> 5, quad = (d0 >> 3) & 3, jb = d0 & 7;
    const int tt = r >> 4, col = r & 15;
    const size_t idx = (size_t)tt * 4096 + (size_t)((kk * 4 + quad) * 16 + col) * 8 + jb;
    *(ushort4*)(Wb + idx) = o;
    float s = v.x*v.x + v.y*v.y + v.z*v.z + v.w*v.w;
    #pragma unroll
    for (int off = 32; off > 0; off >>= 1) s += __shfl_down(s, off);
    if (lane == 0) wnorm[r] = s;
    if (blockIdx.x == 0) {
        #pragma unroll
        for (int q = 0; q < 4; ++q) enc_sum[threadIdx.x * 4 + q] = 0.0f;
    }
}

// ---------------- fused MFMA GEMM + top-k + fp64 refine + quantize + loss ----
// 512 thr = 8 waves: row-group g = wave&3 (16 rows), code-half h = wave>>2
// (512 codes). 64 rows/block (= 64 consecutive hw of one image b), grid 512.
// A fragments built directly from NCHW x (per-lane scalar loads, 64B-segment
// coalesced). B staged via async global_load_lds, double-buffered 2x32KB.
// Epilogue: candidate merge -> fp64 refine (row x dim-slice split) -> top-2
// -> quantize + loss + NCHW write through pad-65 LDS transpose tile.
__global__ __launch_bounds__(512, 4) void gemm_topk_quant(
    const float* __restrict__ x, const unsigned short* __restrict__ Wb,
    const float* __restrict__ wnorm, const float* __restrict__ Wm,
    float* __restrict__ enc_sum,
    int* __restrict__ i0w, int* __restrict__ i1w,
    float* __restrict__ w0w, float* __restrict__ w1w,
    float* __restrict__ outq, float* __restrict__ loss_part)
{
    __shared__ __align__(16) char lds[65536];
    // post-loop aliases (all used only after the main loop's final barrier)
    float*  sCd   = (float*)lds;                 // [64*96] f32 = 24576 B (dies at merge)
    double* pd    = (double*)lds;                // [512*8] f64 = 32768 B (after merge)
    double* pr    = (double*)(lds + 32768);      // [512]   f64 =  4096 B
    int*    mIdx  = (int*)(lds + 36864);         // [512]   i32 =  2048 B
    double* rd    = (double*)(lds + 40960);      // [64*8]  f64 =  4096 B
    double* rnr   = (double*)(lds + 45056);      // [64]    f64 =   512 B
    int*    s0    = (int*)(lds + 45568);         // [64]
    int*    s1    = (int*)(lds + 45824);         // [64]
    float*  sw0   = (float*)(lds + 46080);       // [64]
    float*  sw1   = (float*)(lds + 46336);       // [64]
    double* sredd = (double*)(lds + 46592);      // [8]
    float*  qtile = (float*)(lds + 47104);       // [64][65] f32 = 16640 B -> ends 63744

    const int t    = threadIdx.x;
    const int wave = t >> 6;
    const int g    = wave & 3;
    const int h    = wave >> 2;
    const int lane = t & 63;
    const int col  = lane & 15;
    const int quad = lane >> 4;
    const int r0   = blockIdx.x * 64;
    const int b    = r0 >> 10;
    const int hw0  = r0 & 1023;
    const float* xblk = x + (size_t)b * 262144 + hw0;   // + d*1024 + hw_local

    // ---- A fragments: 16 rows x K=256 straight from NCHW x, bf16 inline ----
    short8 af[8];
    {
        const float* xa = xblk + g * 16 + col;          // this lane's row
        #pragma unroll
        for (int kk = 0; kk < 8; ++kk) {
            short8 f;
            #pragma unroll
            for (int j = 0; j < 8; ++j) {
                float v = xa[(size_t)(kk * 32 + quad * 8 + j) * 1024];
                f[j] = (short)f2bf(v);
            }
            af[kk] = f;
        }
    }

    float m0[4], m1[4], m2[4];
    #pragma unroll
    for (int r = 0; r < 4; ++r) { m0[r] = 3.4e38f; m1[r] = 3.4e38f; m2[r] = 3.4e38f; }

    // staging: wave (X=h, sub=g) copies 4KB of its half's 16KB region per iter
    const char* wb_bytes = (const char*)Wb;
    const int X = h, sub = g;
    const size_t src_wave = (size_t)X * 262144 + (size_t)sub * 4096;
    const int    lds_wave = X * 16384 + sub * 4096;

    // prologue: stage iter 0 into buf0
    {
        const char* src = wb_bytes + src_wave;
        char* dstl = lds + lds_wave;
        #pragma unroll
        for (int q = 0; q < 4; ++q)
            gl_lds16(src + q * 1024 + lane * 16, dstl + q * 1024);
    }
    __syncthreads();

    for (int cc = 0; cc < 16; ++cc) {
        if (cc < 15) {
            const char* src = wb_bytes + src_wave + (size_t)(cc + 1) * 16384;
            char* dstl = lds + ((cc + 1) & 1) * 32768 + lds_wave;
            #pragma unroll
            for (int q = 0; q < 4; ++q)
                gl_lds16(src + q * 1024 + lane * 16, dstl + q * 1024);
        }
        const char* bb = lds + (cc & 1) * 32768 + h * 16384;
        f32x4 acc0 = {0.f, 0.f, 0.f, 0.f};
        f32x4 acc1 = {0.f, 0.f, 0.f, 0.f};
        #pragma unroll
        for (int kk = 0; kk < 8; ++kk) {
            short8 b0 = *(const short8*)(bb + kk * 1024 + lane * 16);
            short8 b1 = *(const short8*)(bb + 8192 + kk * 1024 + lane * 16);
            acc0 = __builtin_amdgcn_mfma_f32_16x16x32_bf16(af[kk], b0, acc0, 0, 0, 0);
            acc1 = __builtin_amdgcn_mfma_f32_16x16x32_bf16(af[kk], b1, acc1, 0, 0, 0);
        }
        const int code0 = h * 512 + cc * 32 + col;
        const int code1 = code0 + 16;
        const float wn0 = wnorm[code0];
        const float wn1 = wnorm[code1];
        #pragma unroll
        for (int r = 0; r < 4; ++r) {
            float pv0 = packdi(fmaf(-2.0f, acc0[r], wn0), code0);
            float t0  = fmaxf(m0[r], pv0); m0[r] = fminf(m0[r], pv0);
            float t1  = fmaxf(m1[r], t0);  m1[r] = fminf(m1[r], t0);
            m2[r] = fminf(m2[r], t1);
            float pv1 = packdi(fmaf(-2.0f, acc1[r], wn1), code1);
            t0 = fmaxf(m0[r], pv1); m0[r] = fminf(m0[r], pv1);
            t1 = fmaxf(m1[r], t0);  m1[r] = fminf(m1[r], t0);
            m2[r] = fminf(m2[r], t1);
        }
        __syncthreads();   // staged data for cc+1 visible; buf[cc&1] reads done
    }

    // ---- dump per-lane candidates (LDS reused), merge top-8 per row ----
    #pragma unroll
    for (int r = 0; r < 4; ++r) {
        int rl = g * 16 + quad * 4 + r;
        sCd[rl * 96 + h * 48 + col * 3 + 0] = m0[r];
        sCd[rl * 96 + h * 48 + col * 3 + 1] = m1[r];
        sCd[rl * 96 + h * 48 + col * 3 + 2] = m2[r];
    }
    __syncthreads();

    if (t < 64) {
        float bd[8];
        #pragma unroll
        for (int q = 0; q < 8; ++q) bd[q] = 3.4e38f;
        for (int s = 0; s < 96; ++s) {
            float d = sCd[t * 96 + s];
            if (d < bd[7]) {
                bd[7] = d;
                #pragma unroll
                for (int p = 7; p > 0; --p) {
                    if (bd[p] < bd[p-1]) { float tf = bd[p]; bd[p] = bd[p-1]; bd[p-1] = tf; }
                }
            }
        }
        #pragma unroll
        for (int q = 0; q < 8; ++q)
            mIdx[t * 8 + q] = (int)(__float_as_uint(bd[q]) & 1023u);
    }
    __syncthreads();

    // ---- fp64 refine: thread = (row = t>>3, dim-slice q8 = t&7) ----
    // each x element read once (64 KB/block); partials for all 8 cands
    {
        const int row = t >> 3;
        const int q8  = t & 7;
        int cd[8];
        #pragma unroll
        for (int c8 = 0; c8 < 8; ++c8) cd[c8] = mIdx[row * 8 + c8];
        const float* xr = xblk + row;
        double dot[8], wn[8];
        #pragma unroll
        for (int c8 = 0; c8 < 8; ++c8) { dot[c8] = 0.0; wn[c8] = 0.0; }
        double rn = 0.0;
        for (int j4 = 0; j4 < 8; ++j4) {
            const int d0 = q8 * 32 + j4 * 4;
            const double x0 = (double)xr[(size_t)(d0 + 0) * 1024];
            const double x1 = (double)xr[(size_t)(d0 + 1) * 1024];
            const double x2 = (double)xr[(size_t)(d0 + 2) * 1024];
            const double x3 = (double)xr[(size_t)(d0 + 3) * 1024];
            rn += x0*x0 + x1*x1 + x2*x2 + x3*x3;
            #pragma unroll
            for (int c8 = 0; c8 < 8; ++c8) {
                const float4 wv = *(const float4*)(Wm + (size_t)cd[c8] * 256 + d0);
                dot[c8] += x0 * (double)wv.x + x1 * (double)wv.y
                         + x2 * (double)wv.z + x3 * (double)wv.w;
                wn[c8]  += (double)wv.x * (double)wv.x + (double)wv.y * (double)wv.y
                         + (double)wv.z * (double)wv.z + (double)wv.w * (double)wv.w;
            }
        }
        #pragma unroll
        for (int c8 = 0; c8 < 8; ++c8) pd[t * 8 + c8] = wn[c8] - 2.0 * dot[c8];
        pr[t] = rn;
    }
    __syncthreads();

    // ---- reduce the 8 dim-slices ----
    {
        const int row = t >> 3;
        const int c8  = t & 7;
        double s = 0.0;
        #pragma unroll
        for (int q = 0; q < 8; ++q) s += pd[(row * 8 + q) * 8 + c8];
        rd[row * 8 + c8] = s;
        if (c8 == 0) {
            double rn = 0.0;
            #pragma unroll
            for (int q = 0; q < 8; ++q) rn += pr[row * 8 + q];
            rnr[row] = rn;
        }
    }
    __syncthreads();

    // ---- final per-row top-2 (exact), weights ----
    if (t < 64) {
        double rn = rnr[t];
        double d0 = 1e300, d1 = 1e300; int b0 = 1 << 30, b1 = 1 << 30;
        #pragma unroll
        for (int q = 0; q < 8; ++q) {
            double d = rd[t * 8 + q];
            int    c = mIdx[t * 8 + q];
            if (d < d0 || (d == d0 && c < b0)) { d1 = d0; b1 = b0; d0 = d; b0 = c; }
            else if (d < d1 || (d == d1 && c < b1)) { d1 = d; b1 = c; }
        }
        double D0 = rn + d0;
        double D1 = rn + d1;
        double inv0 = 1.0 / D0, inv1 = 1.0 / D1;
        double nrm = sqrt(inv0 * inv0 + inv1 * inv1);
        if (nrm < 1e-12) nrm = 1e-12;
        float w0 = (float)(inv0 / nrm);
        float w1 = (float)(inv1 / nrm);
        const int r = r0 + t;
        i0w[r] = b0; i1w[r] = b1;
        w0w[r] = w0; w1w[r] = w1;
        s0[t] = b0; s1[t] = b1; sw0[t] = w0; sw1[t] = w1;
        atomicAdd(&enc_sum[b0], w0);
        atomicAdd(&enc_sum[b1], w1);
    }
    __syncthreads();

    // ---- quantize + loss + NCHW write, 4 chunks of 64 channels ----
    double ls = 0.0;
    for (int ch = 0; ch < 4; ++ch) {
        const int c0 = ch * 64;
        #pragma unroll
        for (int p = 0; p < 2; ++p) {
            const int task = p * 512 + t;
            const int hwl  = task >> 4;       // 0..63
            const int cq   = task & 15;       // c-quad within chunk
            const int cA   = c0 + cq * 4;
            const float4 av = *(const float4*)(Wm + (size_t)s0[hwl] * 256 + cA);
            const float4 bv = *(const float4*)(Wm + (size_t)s1[hwl] * 256 + cA);
            const float w0 = sw0[hwl], w1 = sw1[hwl];
            const float* xp = xblk + hwl;
            float q0 = w0 * av.x + w1 * bv.x;
            float q1 = w0 * av.y + w1 * bv.y;
            float q2 = w0 * av.z + w1 * bv.z;
            float q3 = w0 * av.w + w1 * bv.w;
            float e0 = q0 - xp[(size_t)(cA + 0) * 1024];
            float e1 = q1 - xp[(size_t)(cA + 1) * 1024];
            float e2 = q2 - xp[(size_t)(cA + 2) * 1024];
            float e3 = q3 - xp[(size_t)(cA + 3) * 1024];
            ls += (double)(e0*e0 + e1*e1 + e2*e2 + e3*e3);
            qtile[(cq * 4 + 0) * 65 + hwl] = q0;
            qtile[(cq * 4 + 1) * 65 + hwl] = q1;
            qtile[(cq * 4 + 2) * 65 + hwl] = q2;
            qtile[(cq * 4 + 3) * 65 + hwl] = q3;
        }
        __syncthreads();
        #pragma unroll
        for (int p = 0; p < 2; ++p) {
            const int task = p * 512 + t;
            const int cl   = task >> 4;       // channel-local 0..63
            const int hwq  = task & 15;
            f32x4 v;
            v.x = qtile[cl * 65 + hwq * 4 + 0];
            v.y = qtile[cl * 65 + hwq * 4 + 1];
            v.z = qtile[cl * 65 + hwq * 4 + 2];
            v.w = qtile[cl * 65 + hwq * 4 + 3];
            __builtin_nontemporal_store(v,
                (f32x4*)(outq + ((size_t)(b * 256 + c0 + cl)) * 1024 + hw0 + hwq * 4));
        }
        __syncthreads();
    }

    // ---- block loss partial ----
    #pragma unroll
    for (int off = 32; off > 0; off >>= 1) ls += __shfl_down(ls, off);
    if (lane == 0) sredd[wave] = ls;
    __syncthreads();
    if (t == 0) {
        double s = 0.0;
        #pragma unroll
        for (int w = 0; w < 8; ++w) s += sredd[w];
        loss_part[blockIdx.x] = (float)s;
    }
}

// ---------------- streaming encodings write (zeros + two weights per row) ----
__global__ __launch_bounds__(256) void enc_write(
    const int* __restrict__ i0w, const int* __restrict__ i1w,
    const float* __restrict__ w0w, const float* __restrict__ w1w,
    float* __restrict__ enc)
{
    const int wave = threadIdx.x >> 6;
    const int lane = threadIdx.x & 63;
    const int r = blockIdx.x * 4 + wave;
    const int i0 = i0w[r], i1 = i1w[r];
    const float w0 = w0w[r], w1 = w1w[r];
    f32x4* dst = (f32x4*)(enc + (size_t)r * KCODES);
    #pragma unroll
    for (int it = 0; it < 4; ++it) {
        int base = it * 256 + lane * 4;
        f32x4 v;
        v.x = (base + 0 == i0) ? w0 : ((base + 0 == i1) ? w1 : 0.0f);
        v.y = (base + 1 == i0) ? w0 : ((base + 1 == i1) ? w1 : 0.0f);
        v.z = (base + 2 == i0) ? w0 : ((base + 2 == i1) ? w1 : 0.0f);
        v.w = (base + 3 == i0) ? w0 : ((base + 3 == i1) ? w1 : 0.0f);
        __builtin_nontemporal_store(v, &dst[it * 64 + lane]);
    }
}

// ---------------- finalize: loss + perplexity ----------------
__global__ __launch_bounds__(256) void finalize_k(const float* __restrict__ enc_sum,
                                                  const float* __restrict__ loss_part,
                                                  float* __restrict__ out)
{
    __shared__ double sh[256];
    const int t = threadIdx.x;
    double ls = 0.0;
    for (int i = t; i < 512; i += 256) ls += (double)loss_part[i];
    sh[t] = ls; __syncthreads();
    for (int s = 128; s > 0; s >>= 1) { if (t < s) sh[t] += sh[t + s]; __syncthreads(); }
    double loss_sum = sh[0];
    __syncthreads();
    double ps = 0.0;
    for (int k = t; k < KCODES; k += 256) {
        double p = (double)enc_sum[k] / (double)NROWS;
        ps += p * log(p + 1e-10);
    }
    sh[t] = ps; __syncthreads();
    for (int s = 128; s > 0; s >>= 1) { if (t < s) sh[t] += sh[t + s]; __syncthreads(); }
    if (t == 0) {
        out[0]        = (float)(1.25 * loss_sum / 8388608.0);
        out[OUT_PERP] = (float)exp(-sh[0]);
    }
}

extern "C" void kernel_launch(void* const* d_in, const int* in_sizes, int n_in,
                              void* d_out, int out_size, void* d_ws, size_t ws_size,
                              hipStream_t stream)
{
    const float* x  = (const float*)d_in[0];
    const float* Wm = (const float*)d_in[1];
    float* out = (float*)d_out;
    float* ws  = (float*)d_ws;

    unsigned short* Wb      = (unsigned short*)(ws + OFF_WB);
    float*          wnorm   = ws + OFF_WNORM;
    float*          enc_sum = ws + OFF_ENCSUM;
    float*          loss_p  = ws + OFF_LOSSP;
    int*            i0w     = (int*)(ws + OFF_I0);
    int*            i1w     = (int*)(ws + OFF_I1);
    float*          w0w     = ws + OFF_W0;
    float*          w1w     = ws + OFF_W1;

    wprep<<<KCODES / 4, 256, 0, stream>>>(Wm, Wb, wnorm, enc_sum);
    gemm_topk_quant<<<NROWS / 64, 512, 0, stream>>>(x, Wb, wnorm, Wm, enc_sum,
                                                    i0w, i1w, w0w, w1w,
                                                    out + OUT_Q, loss_p);
    enc_write<<<NROWS / 4, 256, 0, stream>>>(i0w, i1w, w0w, w1w, out + OUT_ENC);
    finalize_k<<<1, 256, 0, stream>>>(enc_sum, loss_p, out);
}

// Round 2
// 283.503 us; speedup vs baseline: 1.1423x; 1.1423x over previous
//
#include <hip/hip_runtime.h>
#include <math.h>

// Problem constants (fixed by setup_inputs)
#define NROWS 32768   // 32 * 32 * 32
#define DIMS  256
#define KCODES 1024

typedef __attribute__((ext_vector_type(8))) short short8;   // 8 bf16 = 4 VGPRs
typedef __attribute__((ext_vector_type(4))) float f32x4;    // MFMA C/D & NT stores

// ws layout (float offsets)
static const size_t OFF_WB     = 8388608;                // [1024][256] bf16, MFMA-fragment tile order
static const size_t OFF_WNORM  = OFF_WB + 131072;        // [1024] f32
static const size_t OFF_ENCSUM = OFF_WNORM + 1024;       // [1024]
static const size_t OFF_LOSSP  = OFF_ENCSUM + 1024;      // [512 used]
static const size_t OFF_I0     = OFF_LOSSP + 8192;       // [32768] int
static const size_t OFF_I1     = OFF_I0 + 32768;         // [32768] int
static const size_t OFF_W0     = OFF_I1 + 32768;         // [32768] float
static const size_t OFF_W1     = OFF_W0 + 32768;         // [32768] float
static const size_t OFF_WND    = OFF_W1 + 32768;         // [1024] f64 (2048 floats), 8B aligned

// out layout (float offsets): loss | quantized NCHW | perplexity | encodings
static const size_t OUT_Q    = 1;
static const size_t OUT_PERP = 8388609;
static const size_t OUT_ENC  = 8388610;

__device__ inline unsigned short f2bf(float f) {
    unsigned int u = __float_as_uint(f);
    unsigned int r = u + 0x7FFFu + ((u >> 16) & 1u);   // RNE
    return (unsigned short)(r >> 16);
}

// pack distance (fp32, low 10 mantissa bits cleared) with 10-bit code index.
__device__ inline float packdi(float d, int code) {
    return __uint_as_float((__float_as_uint(d) & 0xFFFFFC00u) | (unsigned)code);
}

// async global->LDS copy, 16B per lane (wave-uniform LDS base + lane*16)
__device__ __forceinline__ void gl_lds16(const void* gsrc, void* ldst) {
    typedef const __attribute__((address_space(1))) unsigned int GU;
    typedef __attribute__((address_space(3))) unsigned int LU;
    __builtin_amdgcn_global_load_lds((GU*)gsrc, (LU*)ldst, 16, 0, 0);
}

// ---------------- W prep: bf16 fragment-order layout + wnorm (f32+f64) ----
__global__ __launch_bounds__(256) void wprep(const float* __restrict__ Wm,
                                             unsigned short* __restrict__ Wb,
                                             float* __restrict__ wnorm,
                                             double* __restrict__ wnormd,
                                             float* __restrict__ enc_sum)
{
    const int r = blockIdx.x * 4 + (threadIdx.x >> 6);
    const int lane = threadIdx.x & 63;
    float4 v = ((const float4*)(Wm + (size_t)r * 256))[lane];
    ushort4 o;
    o.x = f2bf(v.x); o.y = f2bf(v.y); o.z = f2bf(v.z); o.w = f2bf(v.w);
    const int d0 = lane * 4;
    const int kk = d0 >> 5, quad = (d0 >> 3) & 3, jb = d0 & 7;
    const int tt = r >> 4, col = r & 15;
    const size_t idx = (size_t)tt * 4096 + (size_t)((kk * 4 + quad) * 16 + col) * 8 + jb;
    *(ushort4*)(Wb + idx) = o;
    double s = (double)v.x*(double)v.x + (double)v.y*(double)v.y
             + (double)v.z*(double)v.z + (double)v.w*(double)v.w;
    #pragma unroll
    for (int off = 32; off > 0; off >>= 1) s += __shfl_down(s, off);
    if (lane == 0) { wnormd[r] = s; wnorm[r] = (float)s; }
    if (blockIdx.x == 0) {
        #pragma unroll
        for (int q = 0; q < 4; ++q) enc_sum[threadIdx.x * 4 + q] = 0.0f;
    }
}

// ---------------- fused MFMA GEMM + top-k + fp64 refine + quantize + loss ----
// 512 thr = 8 waves. Two thread mappings:
//   MFMA:   wave w: g=w&3 (16-row group), h=w>>2 (512-code half); lane: col,quad
//   refine: row = t>>3 (0..63), q8 = t&7 (two 16-dim slices: q8*16 & 128+q8*16)
// Each thread holds xs[32] f32 of x for its (row, slices) — loaded ONCE at start.
// A fragments built via a transient bf16 LDS x-tile (aliases buf1, consumed
// before cc=0 staging overwrites it). Refine & loss read x only from xs.
__global__ __launch_bounds__(512, 4) void gemm_topk_quant(
    const float* __restrict__ x, const unsigned short* __restrict__ Wb,
    const float* __restrict__ wnorm, const double* __restrict__ wnd,
    const float* __restrict__ Wm,
    float* __restrict__ enc_sum,
    int* __restrict__ i0w, int* __restrict__ i1w,
    float* __restrict__ w0w, float* __restrict__ w1w,
    float* __restrict__ outq, float* __restrict__ loss_part)
{
    __shared__ __align__(16) char lds[65536];
    // post-loop aliases (all used only after the main loop's final barrier)
    float*  sCd   = (float*)lds;                 // [64*96] f32 = 24576 B (dies at merge)
    float*  qtile = (float*)lds;                 // [128][67] f32 = 34304 B (epilogue only)
    double* rd    = (double*)(lds + 34816);      // [512] f64 -> 38912
    double* rnr   = (double*)(lds + 38912);      // [64]  f64 -> 39424
    int*    s0    = (int*)(lds + 39424);         // [64] -> 39680
    int*    s1    = (int*)(lds + 39680);         // [64] -> 39936
    float*  sw0   = (float*)(lds + 39936);       // [64] -> 40192
    float*  sw1   = (float*)(lds + 40192);       // [64] -> 40448
    double* sredd = (double*)(lds + 40448);      // [8]  -> 40512
    int*    mIdx  = (int*)(lds + 40960);         // [512] -> 43008
    unsigned short* xtile = (unsigned short*)(lds + 32768);  // [64][256] bf16, pre-loop only

    const int t    = threadIdx.x;
    const int wave = t >> 6;
    const int g    = wave & 3;
    const int h    = wave >> 2;
    const int lane = t & 63;
    const int col  = lane & 15;
    const int quad = lane >> 4;
    const int r0   = blockIdx.x * 64;
    const int b    = r0 >> 10;
    const int hw0  = r0 & 1023;
    const float* xblk = x + (size_t)b * 262144 + hw0;   // + d*1024 + hw_local

    const int row = t >> 3;   // refine/epilogue row (hw local)
    const int q8  = t & 7;    // dim-slice

    // ---- issue prologue B staging (buf0 @ lds[0..32K]) first ----
    const char* wb_bytes = (const char*)Wb;
    const size_t src_wave = (size_t)h * 262144 + (size_t)g * 4096;
    const int    lds_wave = h * 16384 + g * 4096;
    {
        const char* src = wb_bytes + src_wave;
        char* dstl = lds + lds_wave;
        #pragma unroll
        for (int q = 0; q < 4; ++q)
            gl_lds16(src + q * 1024 + lane * 16, dstl + q * 1024);
    }

    // ---- xs: this thread's 32 x values (row, dims p2*128 + q8*16 + j) ----
    float xs[32];
    {
        const float* xr = xblk + row;
        #pragma unroll
        for (int p2 = 0; p2 < 2; ++p2)
            #pragma unroll
            for (int j = 0; j < 16; ++j)
                xs[p2 * 16 + j] = xr[(size_t)(p2 * 128 + q8 * 16 + j) * 1024];
    }

    // ---- build bf16 x-tile [64][256] in LDS (upper 32K, aliases buf1) ----
    #pragma unroll
    for (int p2 = 0; p2 < 2; ++p2)
        #pragma unroll
        for (int j4 = 0; j4 < 4; ++j4) {
            ushort4 o;
            o.x = f2bf(xs[p2 * 16 + j4 * 4 + 0]);
            o.y = f2bf(xs[p2 * 16 + j4 * 4 + 1]);
            o.z = f2bf(xs[p2 * 16 + j4 * 4 + 2]);
            o.w = f2bf(xs[p2 * 16 + j4 * 4 + 3]);
            *(ushort4*)(xtile + row * 256 + p2 * 128 + q8 * 16 + j4 * 4) = o;
        }
    __syncthreads();

    // ---- A fragments from x-tile (both halves read the same 16 rows) ----
    short8 af[8];
    #pragma unroll
    for (int kk = 0; kk < 8; ++kk)
        af[kk] = *(const short8*)(xtile + (g * 16 + col) * 256 + kk * 32 + quad * 8);
    __syncthreads();   // af reads done; buf0 staged (vmcnt drained). cc=0 may now overwrite xtile.

    float m0[4], m1[4], m2[4];
    #pragma unroll
    for (int r = 0; r < 4; ++r) { m0[r] = 3.4e38f; m1[r] = 3.4e38f; m2[r] = 3.4e38f; }

    for (int cc = 0; cc < 16; ++cc) {
        if (cc < 15) {
            const char* src = wb_bytes + src_wave + (size_t)(cc + 1) * 16384;
            char* dstl = lds + ((cc + 1) & 1) * 32768 + lds_wave;
            #pragma unroll
            for (int q = 0; q < 4; ++q)
                gl_lds16(src + q * 1024 + lane * 16, dstl + q * 1024);
        }
        const char* bb = lds + (cc & 1) * 32768 + h * 16384;
        f32x4 acc0 = {0.f, 0.f, 0.f, 0.f};
        f32x4 acc1 = {0.f, 0.f, 0.f, 0.f};
        #pragma unroll
        for (int kk = 0; kk < 8; ++kk) {
            short8 b0 = *(const short8*)(bb + kk * 1024 + lane * 16);
            short8 b1 = *(const short8*)(bb + 8192 + kk * 1024 + lane * 16);
            acc0 = __builtin_amdgcn_mfma_f32_16x16x32_bf16(af[kk], b0, acc0, 0, 0, 0);
            acc1 = __builtin_amdgcn_mfma_f32_16x16x32_bf16(af[kk], b1, acc1, 0, 0, 0);
        }
        const int code0 = h * 512 + cc * 32 + col;
        const int code1 = code0 + 16;
        const float wn0 = wnorm[code0];
        const float wn1 = wnorm[code1];
        #pragma unroll
        for (int r = 0; r < 4; ++r) {
            float pv0 = packdi(fmaf(-2.0f, acc0[r], wn0), code0);
            float t0  = fmaxf(m0[r], pv0); m0[r] = fminf(m0[r], pv0);
            float t1  = fmaxf(m1[r], t0);  m1[r] = fminf(m1[r], t0);
            m2[r] = fminf(m2[r], t1);
            float pv1 = packdi(fmaf(-2.0f, acc1[r], wn1), code1);
            t0 = fmaxf(m0[r], pv1); m0[r] = fminf(m0[r], pv1);
            t1 = fmaxf(m1[r], t0);  m1[r] = fminf(m1[r], t0);
            m2[r] = fminf(m2[r], t1);
        }
        __syncthreads();   // staged data for cc+1 visible; buf[cc&1] reads done
    }

    // ---- dump per-lane candidates (LDS reused), merge top-8 per row ----
    #pragma unroll
    for (int r = 0; r < 4; ++r) {
        int rl = g * 16 + quad * 4 + r;
        sCd[rl * 96 + h * 48 + col * 3 + 0] = m0[r];
        sCd[rl * 96 + h * 48 + col * 3 + 1] = m1[r];
        sCd[rl * 96 + h * 48 + col * 3 + 2] = m2[r];
    }
    __syncthreads();

    if (t < 64) {
        float bd[8];
        #pragma unroll
        for (int q = 0; q < 8; ++q) bd[q] = 3.4e38f;
        for (int s = 0; s < 96; ++s) {
            float d = sCd[t * 96 + s];
            if (d < bd[7]) {
                bd[7] = d;
                #pragma unroll
                for (int p = 7; p > 0; --p) {
                    if (bd[p] < bd[p-1]) { float tf = bd[p]; bd[p] = bd[p-1]; bd[p-1] = tf; }
                }
            }
        }
        #pragma unroll
        for (int q = 0; q < 8; ++q)
            mIdx[t * 8 + q] = (int)(__float_as_uint(bd[q]) & 1023u);
    }
    __syncthreads();

    // ---- fp64 refine from xs regs: partial dots per slice, shfl_xor reduce ----
    {
        int cd[8];
        #pragma unroll
        for (int c8 = 0; c8 < 8; ++c8) cd[c8] = mIdx[row * 8 + c8];
        double dot[8];
        #pragma unroll
        for (int c8 = 0; c8 < 8; ++c8) dot[c8] = 0.0;
        double rn = 0.0;
        #pragma unroll
        for (int v = 0; v < 8; ++v) {
            const int d0 = (v >> 2) * 128 + q8 * 16 + (v & 3) * 4;
            const double x0 = (double)xs[v * 4 + 0];
            const double x1 = (double)xs[v * 4 + 1];
            const double x2 = (double)xs[v * 4 + 2];
            const double x3 = (double)xs[v * 4 + 3];
            rn += x0*x0 + x1*x1 + x2*x2 + x3*x3;
            #pragma unroll
            for (int c8 = 0; c8 < 8; ++c8) {
                const float4 wv = *(const float4*)(Wm + (size_t)cd[c8] * 256 + d0);
                dot[c8] += x0 * (double)wv.x + x1 * (double)wv.y
                         + x2 * (double)wv.z + x3 * (double)wv.w;
            }
        }
        #pragma unroll
        for (int m = 1; m < 8; m <<= 1) {
            #pragma unroll
            for (int c8 = 0; c8 < 8; ++c8) dot[c8] += __shfl_xor(dot[c8], m);
            rn += __shfl_xor(rn, m);
        }
        // static select of this thread's candidate (avoid dynamic reg indexing)
        int myc = 0; double mydot = 0.0;
        #pragma unroll
        for (int c8 = 0; c8 < 8; ++c8)
            if (q8 == c8) { myc = cd[c8]; mydot = dot[c8]; }
        rd[row * 8 + q8] = wnd[myc] - 2.0 * mydot;
        if (q8 == 0) rnr[row] = rn;
    }
    __syncthreads();

    // ---- final per-row top-2 (exact), weights ----
    if (t < 64) {
        double rn = rnr[t];
        double d0 = 1e300, d1 = 1e300; int b0 = 1 << 30, b1 = 1 << 30;
        #pragma unroll
        for (int q = 0; q < 8; ++q) {
            double d = rd[t * 8 + q];
            int    c = mIdx[t * 8 + q];
            if (d < d0 || (d == d0 && c < b0)) { d1 = d0; b1 = b0; d0 = d; b0 = c; }
            else if (d < d1 || (d == d1 && c < b1)) { d1 = d; b1 = c; }
        }
        double D0 = rn + d0;
        double D1 = rn + d1;
        double inv0 = 1.0 / D0, inv1 = 1.0 / D1;
        double nrm = sqrt(inv0 * inv0 + inv1 * inv1);
        if (nrm < 1e-12) nrm = 1e-12;
        float w0 = (float)(inv0 / nrm);
        float w1 = (float)(inv1 / nrm);
        const int r = r0 + t;
        i0w[r] = b0; i1w[r] = b1;
        w0w[r] = w0; w1w[r] = w1;
        s0[t] = b0; s1[t] = b1; sw0[t] = w0; sw1[t] = w1;
        atomicAdd(&enc_sum[b0], w0);
        atomicAdd(&enc_sum[b1], w1);
    }
    __syncthreads();

    // ---- quantize + loss (from xs) + NCHW write, 2 chunks of 128 channels ----
    double ls = 0.0;
    #pragma unroll
    for (int p2 = 0; p2 < 2; ++p2) {
        const int   cA = s0[row], cB = s1[row];
        const float w0 = sw0[row], w1 = sw1[row];
        const float* W0 = Wm + (size_t)cA * 256 + p2 * 128 + q8 * 16;
        const float* W1 = Wm + (size_t)cB * 256 + p2 * 128 + q8 * 16;
        #pragma unroll
        for (int v4 = 0; v4 < 4; ++v4) {
            const float4 a  = *(const float4*)(W0 + v4 * 4);
            const float4 bv = *(const float4*)(W1 + v4 * 4);
            float q0 = w0 * a.x + w1 * bv.x;
            float q1 = w0 * a.y + w1 * bv.y;
            float q2 = w0 * a.z + w1 * bv.z;
            float q3 = w0 * a.w + w1 * bv.w;
            float e0 = q0 - xs[p2 * 16 + v4 * 4 + 0];
            float e1 = q1 - xs[p2 * 16 + v4 * 4 + 1];
            float e2 = q2 - xs[p2 * 16 + v4 * 4 + 2];
            float e3 = q3 - xs[p2 * 16 + v4 * 4 + 3];
            ls += (double)(e0*e0 + e1*e1 + e2*e2 + e3*e3);
            const int dl = q8 * 16 + v4 * 4;
            qtile[(dl + 0) * 67 + row] = q0;
            qtile[(dl + 1) * 67 + row] = q1;
            qtile[(dl + 2) * 67 + row] = q2;
            qtile[(dl + 3) * 67 + row] = q3;
        }
        __syncthreads();
        #pragma unroll
        for (int p = 0; p < 4; ++p) {
            const int task = p * 512 + t;
            const int cl   = task >> 4;       // channel-local 0..127
            const int hwq  = task & 15;
            f32x4 v;
            v.x = qtile[cl * 67 + hwq * 4 + 0];
            v.y = qtile[cl * 67 + hwq * 4 + 1];
            v.z = qtile[cl * 67 + hwq * 4 + 2];
            v.w = qtile[cl * 67 + hwq * 4 + 3];
            __builtin_nontemporal_store(v,
                (f32x4*)(outq + ((size_t)(b * 256 + p2 * 128 + cl)) * 1024 + hw0 + hwq * 4));
        }
        __syncthreads();
    }

    // ---- block loss partial ----
    #pragma unroll
    for (int off = 32; off > 0; off >>= 1) ls += __shfl_down(ls, off);
    if (lane == 0) sredd[wave] = ls;
    __syncthreads();
    if (t == 0) {
        double s = 0.0;
        #pragma unroll
        for (int w = 0; w < 8; ++w) s += sredd[w];
        loss_part[blockIdx.x] = (float)s;
    }
}

// ---------------- streaming encodings write (zeros + two weights per row) ----
__global__ __launch_bounds__(256) void enc_write(
    const int* __restrict__ i0w, const int* __restrict__ i1w,
    const float* __restrict__ w0w, const float* __restrict__ w1w,
    float* __restrict__ enc)
{
    const int wave = threadIdx.x >> 6;
    const int lane = threadIdx.x & 63;
    const int r = blockIdx.x * 4 + wave;
    const int i0 = i0w[r], i1 = i1w[r];
    const float w0 = w0w[r], w1 = w1w[r];
    f32x4* dst = (f32x4*)(enc + (size_t)r * KCODES);
    #pragma unroll
    for (int it = 0; it < 4; ++it) {
        int base = it * 256 + lane * 4;
        f32x4 v;
        v.x = (base + 0 == i0) ? w0 : ((base + 0 == i1) ? w1 : 0.0f);
        v.y = (base + 1 == i0) ? w0 : ((base + 1 == i1) ? w1 : 0.0f);
        v.z = (base + 2 == i0) ? w0 : ((base + 2 == i1) ? w1 : 0.0f);
        v.w = (base + 3 == i0) ? w0 : ((base + 3 == i1) ? w1 : 0.0f);
        __builtin_nontemporal_store(v, &dst[it * 64 + lane]);
    }
}

// ---------------- finalize: loss + perplexity ----------------
__global__ __launch_bounds__(256) void finalize_k(const float* __restrict__ enc_sum,
                                                  const float* __restrict__ loss_part,
                                                  float* __restrict__ out)
{
    __shared__ double sh[256];
    const int t = threadIdx.x;
    double ls = 0.0;
    for (int i = t; i < 512; i += 256) ls += (double)loss_part[i];
    sh[t] = ls; __syncthreads();
    for (int s = 128; s > 0; s >>= 1) { if (t < s) sh[t] += sh[t + s]; __syncthreads(); }
    double loss_sum = sh[0];
    __syncthreads();
    double ps = 0.0;
    for (int k = t; k < KCODES; k += 256) {
        double p = (double)enc_sum[k] / (double)NROWS;
        ps += p * log(p + 1e-10);
    }
    sh[t] = ps; __syncthreads();
    for (int s = 128; s > 0; s >>= 1) { if (t < s) sh[t] += sh[t + s]; __syncthreads(); }
    if (t == 0) {
        out[0]        = (float)(1.25 * loss_sum / 8388608.0);
        out[OUT_PERP] = (float)exp(-sh[0]);
    }
}

extern "C" void kernel_launch(void* const* d_in, const int* in_sizes, int n_in,
                              void* d_out, int out_size, void* d_ws, size_t ws_size,
                              hipStream_t stream)
{
    const float* x  = (const float*)d_in[0];
    const float* Wm = (const float*)d_in[1];
    float* out = (float*)d_out;
    float* ws  = (float*)d_ws;

    unsigned short* Wb      = (unsigned short*)(ws + OFF_WB);
    float*          wnorm   = ws + OFF_WNORM;
    float*          enc_sum = ws + OFF_ENCSUM;
    float*          loss_p  = ws + OFF_LOSSP;
    int*            i0w     = (int*)(ws + OFF_I0);
    int*            i1w     = (int*)(ws + OFF_I1);
    float*          w0w     = ws + OFF_W0;
    float*          w1w     = ws + OFF_W1;
    double*         wnd     = (double*)(ws + OFF_WND);

    wprep<<<KCODES / 4, 256, 0, stream>>>(Wm, Wb, wnorm, wnd, enc_sum);
    gemm_topk_quant<<<NROWS / 64, 512, 0, stream>>>(x, Wb, wnorm, wnd, Wm, enc_sum,
                                                    i0w, i1w, w0w, w1w,
                                                    out + OUT_Q, loss_p);
    enc_write<<<NROWS / 4, 256, 0, stream>>>(i0w, i1w, w0w, w1w, out + OUT_ENC);
    finalize_k<<<1, 256, 0, stream>>>(enc_sum, loss_p, out);
}

// Round 3
// 272.263 us; speedup vs baseline: 1.1894x; 1.0413x over previous
//
#include <hip/hip_runtime.h>
#include <math.h>

// Problem constants (fixed by setup_inputs)
#define NROWS 32768   // 32 * 32 * 32
#define DIMS  256
#define KCODES 1024

typedef __attribute__((ext_vector_type(8))) short short8;   // 8 bf16 = 4 VGPRs
typedef __attribute__((ext_vector_type(4))) float f32x4;    // MFMA C/D & NT stores

// ws layout (float offsets)
static const size_t OFF_WB     = 8388608;                // [1024][256] bf16, MFMA-fragment tile order
static const size_t OFF_WNORM  = OFF_WB + 131072;        // [1024] f32
static const size_t OFF_ENCSUM = OFF_WNORM + 1024;       // [1024]
static const size_t OFF_LOSSP  = OFF_ENCSUM + 1024;      // [512 used]
static const size_t OFF_WND    = OFF_LOSSP + 8192;       // [1024] f64 (2048 floats), 8B aligned

// out layout (float offsets): loss | quantized NCHW | perplexity | encodings
static const size_t OUT_Q    = 1;
static const size_t OUT_PERP = 8388609;
static const size_t OUT_ENC  = 8388610;

__device__ inline unsigned short f2bf(float f) {
    unsigned int u = __float_as_uint(f);
    unsigned int r = u + 0x7FFFu + ((u >> 16) & 1u);   // RNE
    return (unsigned short)(r >> 16);
}

// pack distance (fp32, low 10 mantissa bits cleared) with 10-bit code index.
__device__ inline float packdi(float d, int code) {
    return __uint_as_float((__float_as_uint(d) & 0xFFFFFC00u) | (unsigned)code);
}

// async global->LDS copy, 16B per lane (wave-uniform LDS base + lane*16)
__device__ __forceinline__ void gl_lds16(const void* gsrc, void* ldst) {
    typedef const __attribute__((address_space(1))) unsigned int GU;
    typedef __attribute__((address_space(3))) unsigned int LU;
    __builtin_amdgcn_global_load_lds((GU*)gsrc, (LU*)ldst, 16, 0, 0);
}

// ---------------- W prep: bf16 fragment-order layout + wnorm (f32+f64) ----
__global__ __launch_bounds__(256) void wprep(const float* __restrict__ Wm,
                                             unsigned short* __restrict__ Wb,
                                             float* __restrict__ wnorm,
                                             double* __restrict__ wnormd,
                                             float* __restrict__ enc_sum)
{
    const int r = blockIdx.x * 4 + (threadIdx.x >> 6);
    const int lane = threadIdx.x & 63;
    float4 v = ((const float4*)(Wm + (size_t)r * 256))[lane];
    ushort4 o;
    o.x = f2bf(v.x); o.y = f2bf(v.y); o.z = f2bf(v.z); o.w = f2bf(v.w);
    const int d0 = lane * 4;
    const int kk = d0 >> 5, quad = (d0 >> 3) & 3, jb = d0 & 7;
    const int tt = r >> 4, col = r & 15;
    const size_t idx = (size_t)tt * 4096 + (size_t)((kk * 4 + quad) * 16 + col) * 8 + jb;
    *(ushort4*)(Wb + idx) = o;
    double s = (double)v.x*(double)v.x + (double)v.y*(double)v.y
             + (double)v.z*(double)v.z + (double)v.w*(double)v.w;
    #pragma unroll
    for (int off = 32; off > 0; off >>= 1) s += __shfl_down(s, off);
    if (lane == 0) { wnormd[r] = s; wnorm[r] = (float)s; }
    if (blockIdx.x == 0) {
        #pragma unroll
        for (int q = 0; q < 4; ++q) enc_sum[threadIdx.x * 4 + q] = 0.0f;
    }
}

// ---------------- fused MFMA GEMM + top-k + fp64 refine + enc + quantize + loss ----
// 512 thr = 8 waves. Two thread mappings:
//   MFMA:   wave w: g=w&3 (16-row group), h=w>>2 (512-code half); lane: col,quad
//   refine: row = t>>3 (0..63), q8 = t&7 (two 16-dim slices: q8*16 & 128+q8*16)
// Each thread holds xs[32] f32 of x for its (row, slices) — loaded ONCE at start.
// A fragments built via a transient bf16 LDS x-tile (aliases buf1, consumed
// before cc=0 staging overwrites it). Refine & loss read x only from xs.
// Encodings rows (64 x 4KB, contiguous) are written here with coalesced NT
// stores right after top-2 — they drain under the quantize phase.
__global__ __launch_bounds__(512, 4) void gemm_topk_quant(
    const float* __restrict__ x, const unsigned short* __restrict__ Wb,
    const float* __restrict__ wnorm, const double* __restrict__ wnd,
    const float* __restrict__ Wm,
    float* __restrict__ enc_sum,
    float* __restrict__ enc,
    float* __restrict__ outq, float* __restrict__ loss_part)
{
    __shared__ __align__(16) char lds[65536];
    // post-loop aliases (all used only after the main loop's final barrier)
    float*  sCd   = (float*)lds;                 // [64*96] f32 = 24576 B (dies at merge)
    float*  qtile = (float*)lds;                 // [128][67] f32 = 34304 B (epilogue only)
    double* rd    = (double*)(lds + 34816);      // [512] f64 -> 38912
    double* rnr   = (double*)(lds + 38912);      // [64]  f64 -> 39424
    int*    s0    = (int*)(lds + 39424);         // [64] -> 39680
    int*    s1    = (int*)(lds + 39680);         // [64] -> 39936
    float*  sw0   = (float*)(lds + 39936);       // [64] -> 40192
    float*  sw1   = (float*)(lds + 40192);       // [64] -> 40448
    double* sredd = (double*)(lds + 40448);      // [8]  -> 40512
    int*    mIdx  = (int*)(lds + 40960);         // [512] -> 43008
    unsigned short* xtile = (unsigned short*)(lds + 32768);  // [64][256] bf16, pre-loop only

    const int t    = threadIdx.x;
    const int wave = t >> 6;
    const int g    = wave & 3;
    const int h    = wave >> 2;
    const int lane = t & 63;
    const int col  = lane & 15;
    const int quad = lane >> 4;
    const int r0   = blockIdx.x * 64;
    const int b    = r0 >> 10;
    const int hw0  = r0 & 1023;
    const float* xblk = x + (size_t)b * 262144 + hw0;   // + d*1024 + hw_local

    const int row = t >> 3;   // refine/epilogue row (hw local)
    const int q8  = t & 7;    // dim-slice

    // ---- issue prologue B staging (buf0 @ lds[0..32K]) first ----
    const char* wb_bytes = (const char*)Wb;
    const size_t src_wave = (size_t)h * 262144 + (size_t)g * 4096;
    const int    lds_wave = h * 16384 + g * 4096;
    {
        const char* src = wb_bytes + src_wave;
        char* dstl = lds + lds_wave;
        #pragma unroll
        for (int q = 0; q < 4; ++q)
            gl_lds16(src + q * 1024 + lane * 16, dstl + q * 1024);
    }

    // ---- xs: this thread's 32 x values (row, dims p2*128 + q8*16 + j) ----
    float xs[32];
    {
        const float* xr = xblk + row;
        #pragma unroll
        for (int p2 = 0; p2 < 2; ++p2)
            #pragma unroll
            for (int j = 0; j < 16; ++j)
                xs[p2 * 16 + j] = xr[(size_t)(p2 * 128 + q8 * 16 + j) * 1024];
    }

    // ---- build bf16 x-tile [64][256] in LDS (upper 32K, aliases buf1) ----
    #pragma unroll
    for (int p2 = 0; p2 < 2; ++p2)
        #pragma unroll
        for (int j4 = 0; j4 < 4; ++j4) {
            ushort4 o;
            o.x = f2bf(xs[p2 * 16 + j4 * 4 + 0]);
            o.y = f2bf(xs[p2 * 16 + j4 * 4 + 1]);
            o.z = f2bf(xs[p2 * 16 + j4 * 4 + 2]);
            o.w = f2bf(xs[p2 * 16 + j4 * 4 + 3]);
            *(ushort4*)(xtile + row * 256 + p2 * 128 + q8 * 16 + j4 * 4) = o;
        }
    __syncthreads();

    // ---- A fragments from x-tile (both halves read the same 16 rows) ----
    short8 af[8];
    #pragma unroll
    for (int kk = 0; kk < 8; ++kk)
        af[kk] = *(const short8*)(xtile + (g * 16 + col) * 256 + kk * 32 + quad * 8);
    __syncthreads();   // af reads done; buf0 staged (vmcnt drained). cc=0 may now overwrite xtile.

    float m0[4], m1[4], m2[4];
    #pragma unroll
    for (int r = 0; r < 4; ++r) { m0[r] = 3.4e38f; m1[r] = 3.4e38f; m2[r] = 3.4e38f; }

    for (int cc = 0; cc < 16; ++cc) {
        if (cc < 15) {
            const char* src = wb_bytes + src_wave + (size_t)(cc + 1) * 16384;
            char* dstl = lds + ((cc + 1) & 1) * 32768 + lds_wave;
            #pragma unroll
            for (int q = 0; q < 4; ++q)
                gl_lds16(src + q * 1024 + lane * 16, dstl + q * 1024);
        }
        const char* bb = lds + (cc & 1) * 32768 + h * 16384;
        f32x4 acc0 = {0.f, 0.f, 0.f, 0.f};
        f32x4 acc1 = {0.f, 0.f, 0.f, 0.f};
        #pragma unroll
        for (int kk = 0; kk < 8; ++kk) {
            short8 b0 = *(const short8*)(bb + kk * 1024 + lane * 16);
            short8 b1 = *(const short8*)(bb + 8192 + kk * 1024 + lane * 16);
            acc0 = __builtin_amdgcn_mfma_f32_16x16x32_bf16(af[kk], b0, acc0, 0, 0, 0);
            acc1 = __builtin_amdgcn_mfma_f32_16x16x32_bf16(af[kk], b1, acc1, 0, 0, 0);
        }
        const int code0 = h * 512 + cc * 32 + col;
        const int code1 = code0 + 16;
        const float wn0 = wnorm[code0];
        const float wn1 = wnorm[code1];
        #pragma unroll
        for (int r = 0; r < 4; ++r) {
            float pv0 = packdi(fmaf(-2.0f, acc0[r], wn0), code0);
            float t0  = fmaxf(m0[r], pv0); m0[r] = fminf(m0[r], pv0);
            float t1  = fmaxf(m1[r], t0);  m1[r] = fminf(m1[r], t0);
            m2[r] = fminf(m2[r], t1);
            float pv1 = packdi(fmaf(-2.0f, acc1[r], wn1), code1);
            t0 = fmaxf(m0[r], pv1); m0[r] = fminf(m0[r], pv1);
            t1 = fmaxf(m1[r], t0);  m1[r] = fminf(m1[r], t0);
            m2[r] = fminf(m2[r], t1);
        }
        __syncthreads();   // staged data for cc+1 visible; buf[cc&1] reads done
    }

    // ---- dump per-lane candidates (LDS reused), merge top-8 per row ----
    #pragma unroll
    for (int r = 0; r < 4; ++r) {
        int rl = g * 16 + quad * 4 + r;
        sCd[rl * 96 + h * 48 + col * 3 + 0] = m0[r];
        sCd[rl * 96 + h * 48 + col * 3 + 1] = m1[r];
        sCd[rl * 96 + h * 48 + col * 3 + 2] = m2[r];
    }
    __syncthreads();

    if (t < 64) {
        float bd[8];
        #pragma unroll
        for (int q = 0; q < 8; ++q) bd[q] = 3.4e38f;
        for (int s = 0; s < 96; ++s) {
            float d = sCd[t * 96 + s];
            if (d < bd[7]) {
                bd[7] = d;
                #pragma unroll
                for (int p = 7; p > 0; --p) {
                    if (bd[p] < bd[p-1]) { float tf = bd[p]; bd[p] = bd[p-1]; bd[p-1] = tf; }
                }
            }
        }
        #pragma unroll
        for (int q = 0; q < 8; ++q)
            mIdx[t * 8 + q] = (int)(__float_as_uint(bd[q]) & 1023u);
    }
    __syncthreads();

    // ---- fp64 refine from xs regs: partial dots per slice, shfl_xor reduce ----
    {
        int cd[8];
        #pragma unroll
        for (int c8 = 0; c8 < 8; ++c8) cd[c8] = mIdx[row * 8 + c8];
        double dot[8];
        #pragma unroll
        for (int c8 = 0; c8 < 8; ++c8) dot[c8] = 0.0;
        double rn = 0.0;
        #pragma unroll
        for (int v = 0; v < 8; ++v) {
            const int d0 = (v >> 2) * 128 + q8 * 16 + (v & 3) * 4;
            const double x0 = (double)xs[v * 4 + 0];
            const double x1 = (double)xs[v * 4 + 1];
            const double x2 = (double)xs[v * 4 + 2];
            const double x3 = (double)xs[v * 4 + 3];
            rn += x0*x0 + x1*x1 + x2*x2 + x3*x3;
            #pragma unroll
            for (int c8 = 0; c8 < 8; ++c8) {
                const float4 wv = *(const float4*)(Wm + (size_t)cd[c8] * 256 + d0);
                dot[c8] += x0 * (double)wv.x + x1 * (double)wv.y
                         + x2 * (double)wv.z + x3 * (double)wv.w;
            }
        }
        #pragma unroll
        for (int m = 1; m < 8; m <<= 1) {
            #pragma unroll
            for (int c8 = 0; c8 < 8; ++c8) dot[c8] += __shfl_xor(dot[c8], m);
            rn += __shfl_xor(rn, m);
        }
        // static select of this thread's candidate (avoid dynamic reg indexing)
        int myc = 0; double mydot = 0.0;
        #pragma unroll
        for (int c8 = 0; c8 < 8; ++c8)
            if (q8 == c8) { myc = cd[c8]; mydot = dot[c8]; }
        rd[row * 8 + q8] = wnd[myc] - 2.0 * mydot;
        if (q8 == 0) rnr[row] = rn;
    }
    __syncthreads();

    // ---- final per-row top-2 (exact), weights ----
    if (t < 64) {
        double rn = rnr[t];
        double d0 = 1e300, d1 = 1e300; int b0 = 1 << 30, b1 = 1 << 30;
        #pragma unroll
        for (int q = 0; q < 8; ++q) {
            double d = rd[t * 8 + q];
            int    c = mIdx[t * 8 + q];
            if (d < d0 || (d == d0 && c < b0)) { d1 = d0; b1 = b0; d0 = d; b0 = c; }
            else if (d < d1 || (d == d1 && c < b1)) { d1 = d; b1 = c; }
        }
        double D0 = rn + d0;
        double D1 = rn + d1;
        double inv0 = 1.0 / D0, inv1 = 1.0 / D1;
        double nrm = sqrt(inv0 * inv0 + inv1 * inv1);
        if (nrm < 1e-12) nrm = 1e-12;
        float w0 = (float)(inv0 / nrm);
        float w1 = (float)(inv1 / nrm);
        s0[t] = b0; s1[t] = b1; sw0[t] = w0; sw1[t] = w1;
        atomicAdd(&enc_sum[b0], w0);
        atomicAdd(&enc_sum[b1], w1);
    }
    __syncthreads();

    // ---- encodings rows: wave w writes rows w*8..w*8+7, coalesced NT stores ----
    // (fire early: these drain underneath the quantize phase below)
    #pragma unroll
    for (int rr = 0; rr < 8; ++rr) {
        const int rw = wave * 8 + rr;
        const int i0 = s0[rw], i1 = s1[rw];
        const float w0 = sw0[rw], w1 = sw1[rw];
        f32x4* dst = (f32x4*)(enc + (size_t)(r0 + rw) * KCODES);
        #pragma unroll
        for (int it = 0; it < 4; ++it) {
            const int base = it * 256 + lane * 4;
            f32x4 v;
            v.x = (base + 0 == i0) ? w0 : ((base + 0 == i1) ? w1 : 0.0f);
            v.y = (base + 1 == i0) ? w0 : ((base + 1 == i1) ? w1 : 0.0f);
            v.z = (base + 2 == i0) ? w0 : ((base + 2 == i1) ? w1 : 0.0f);
            v.w = (base + 3 == i0) ? w0 : ((base + 3 == i1) ? w1 : 0.0f);
            __builtin_nontemporal_store(v, &dst[it * 64 + lane]);
        }
    }

    // ---- quantize + loss (from xs) + NCHW write, 2 chunks of 128 channels ----
    double ls = 0.0;
    #pragma unroll
    for (int p2 = 0; p2 < 2; ++p2) {
        const int   cA = s0[row], cB = s1[row];
        const float w0 = sw0[row], w1 = sw1[row];
        const float* W0 = Wm + (size_t)cA * 256 + p2 * 128 + q8 * 16;
        const float* W1 = Wm + (size_t)cB * 256 + p2 * 128 + q8 * 16;
        #pragma unroll
        for (int v4 = 0; v4 < 4; ++v4) {
            const float4 a  = *(const float4*)(W0 + v4 * 4);
            const float4 bv = *(const float4*)(W1 + v4 * 4);
            float q0 = w0 * a.x + w1 * bv.x;
            float q1 = w0 * a.y + w1 * bv.y;
            float q2 = w0 * a.z + w1 * bv.z;
            float q3 = w0 * a.w + w1 * bv.w;
            float e0 = q0 - xs[p2 * 16 + v4 * 4 + 0];
            float e1 = q1 - xs[p2 * 16 + v4 * 4 + 1];
            float e2 = q2 - xs[p2 * 16 + v4 * 4 + 2];
            float e3 = q3 - xs[p2 * 16 + v4 * 4 + 3];
            ls += (double)(e0*e0 + e1*e1 + e2*e2 + e3*e3);
            const int dl = q8 * 16 + v4 * 4;
            qtile[(dl + 0) * 67 + row] = q0;
            qtile[(dl + 1) * 67 + row] = q1;
            qtile[(dl + 2) * 67 + row] = q2;
            qtile[(dl + 3) * 67 + row] = q3;
        }
        __syncthreads();
        #pragma unroll
        for (int p = 0; p < 4; ++p) {
            const int task = p * 512 + t;
            const int cl   = task >> 4;       // channel-local 0..127
            const int hwq  = task & 15;
            f32x4 v;
            v.x = qtile[cl * 67 + hwq * 4 + 0];
            v.y = qtile[cl * 67 + hwq * 4 + 1];
            v.z = qtile[cl * 67 + hwq * 4 + 2];
            v.w = qtile[cl * 67 + hwq * 4 + 3];
            __builtin_nontemporal_store(v,
                (f32x4*)(outq + ((size_t)(b * 256 + p2 * 128 + cl)) * 1024 + hw0 + hwq * 4));
        }
        __syncthreads();
    }

    // ---- block loss partial ----
    #pragma unroll
    for (int off = 32; off > 0; off >>= 1) ls += __shfl_down(ls, off);
    if (lane == 0) sredd[wave] = ls;
    __syncthreads();
    if (t == 0) {
        double s = 0.0;
        #pragma unroll
        for (int w = 0; w < 8; ++w) s += sredd[w];
        loss_part[blockIdx.x] = (float)s;
    }
}

// ---------------- finalize: loss + perplexity ----------------
__global__ __launch_bounds__(256) void finalize_k(const float* __restrict__ enc_sum,
                                                  const float* __restrict__ loss_part,
                                                  float* __restrict__ out)
{
    __shared__ double sh[256];
    const int t = threadIdx.x;
    double ls = 0.0;
    for (int i = t; i < 512; i += 256) ls += (double)loss_part[i];
    sh[t] = ls; __syncthreads();
    for (int s = 128; s > 0; s >>= 1) { if (t < s) sh[t] += sh[t + s]; __syncthreads(); }
    double loss_sum = sh[0];
    __syncthreads();
    double ps = 0.0;
    for (int k = t; k < KCODES; k += 256) {
        double p = (double)enc_sum[k] / (double)NROWS;
        ps += p * log(p + 1e-10);
    }
    sh[t] = ps; __syncthreads();
    for (int s = 128; s > 0; s >>= 1) { if (t < s) sh[t] += sh[t + s]; __syncthreads(); }
    if (t == 0) {
        out[0]        = (float)(1.25 * loss_sum / 8388608.0);
        out[OUT_PERP] = (float)exp(-sh[0]);
    }
}

extern "C" void kernel_launch(void* const* d_in, const int* in_sizes, int n_in,
                              void* d_out, int out_size, void* d_ws, size_t ws_size,
                              hipStream_t stream)
{
    const float* x  = (const float*)d_in[0];
    const float* Wm = (const float*)d_in[1];
    float* out = (float*)d_out;
    float* ws  = (float*)d_ws;

    unsigned short* Wb      = (unsigned short*)(ws + OFF_WB);
    float*          wnorm   = ws + OFF_WNORM;
    float*          enc_sum = ws + OFF_ENCSUM;
    float*          loss_p  = ws + OFF_LOSSP;
    double*         wnd     = (double*)(ws + OFF_WND);

    wprep<<<KCODES / 4, 256, 0, stream>>>(Wm, Wb, wnorm, wnd, enc_sum);
    gemm_topk_quant<<<NROWS / 64, 512, 0, stream>>>(x, Wb, wnorm, wnd, Wm, enc_sum,
                                                    out + OUT_ENC, out + OUT_Q, loss_p);
    finalize_k<<<1, 256, 0, stream>>>(enc_sum, loss_p, out);
}

// Round 4
// 263.154 us; speedup vs baseline: 1.2306x; 1.0346x over previous
//
#include <hip/hip_runtime.h>
#include <math.h>

// Problem constants (fixed by setup_inputs)
#define NROWS 32768   // 32 * 32 * 32
#define DIMS  256
#define KCODES 1024

typedef __attribute__((ext_vector_type(8))) short short8;   // 8 bf16 = 4 VGPRs
typedef __attribute__((ext_vector_type(4))) float f32x4;    // MFMA C/D & stores

// ws layout (float offsets)
static const size_t OFF_WB     = 8388608;                // [1024][256] bf16, MFMA-fragment tile order
static const size_t OFF_WNORM  = OFF_WB + 131072;        // [1024] f32
static const size_t OFF_ENCSUM = OFF_WNORM + 1024;       // [1024]
static const size_t OFF_LOSSP  = OFF_ENCSUM + 1024;      // [512 used]
static const size_t OFF_WND    = OFF_LOSSP + 8192;       // [1024] f64 (2048 floats), 8B aligned

// out layout (float offsets): loss | quantized NCHW | perplexity | encodings
static const size_t OUT_Q    = 1;
static const size_t OUT_PERP = 8388609;
static const size_t OUT_ENC  = 8388610;

__device__ inline unsigned short f2bf(float f) {
    unsigned int u = __float_as_uint(f);
    unsigned int r = u + 0x7FFFu + ((u >> 16) & 1u);   // RNE
    return (unsigned short)(r >> 16);
}

// pack distance (fp32, low 10 mantissa bits cleared) with 10-bit code index.
__device__ inline float packdi(float d, int code) {
    return __uint_as_float((__float_as_uint(d) & 0xFFFFFC00u) | (unsigned)code);
}

// async global->LDS copy, 16B per lane (wave-uniform LDS base + lane*16)
__device__ __forceinline__ void gl_lds16(const void* gsrc, void* ldst) {
    typedef const __attribute__((address_space(1))) unsigned int GU;
    typedef __attribute__((address_space(3))) unsigned int LU;
    __builtin_amdgcn_global_load_lds((GU*)gsrc, (LU*)ldst, 16, 0, 0);
}

// ---------------- W prep: bf16 fragment-order layout + wnorm (f32+f64) ----
__global__ __launch_bounds__(256) void wprep(const float* __restrict__ Wm,
                                             unsigned short* __restrict__ Wb,
                                             float* __restrict__ wnorm,
                                             double* __restrict__ wnormd,
                                             float* __restrict__ enc_sum)
{
    const int r = blockIdx.x * 4 + (threadIdx.x >> 6);
    const int lane = threadIdx.x & 63;
    float4 v = ((const float4*)(Wm + (size_t)r * 256))[lane];
    ushort4 o;
    o.x = f2bf(v.x); o.y = f2bf(v.y); o.z = f2bf(v.z); o.w = f2bf(v.w);
    const int d0 = lane * 4;
    const int kk = d0 >> 5, quad = (d0 >> 3) & 3, jb = d0 & 7;
    const int tt = r >> 4, col = r & 15;
    const size_t idx = (size_t)tt * 4096 + (size_t)((kk * 4 + quad) * 16 + col) * 8 + jb;
    *(ushort4*)(Wb + idx) = o;
    double s = (double)v.x*(double)v.x + (double)v.y*(double)v.y
             + (double)v.z*(double)v.z + (double)v.w*(double)v.w;
    #pragma unroll
    for (int off = 32; off > 0; off >>= 1) s += __shfl_down(s, off);
    if (lane == 0) { wnormd[r] = s; wnorm[r] = (float)s; }
    if (blockIdx.x == 0) {
        #pragma unroll
        for (int q = 0; q < 4; ++q) enc_sum[threadIdx.x * 4 + q] = 0.0f;
    }
}

// ---------------- fused MFMA GEMM + top-k + fp64 refine + enc + quantize + loss ----
// 512 thr = 8 waves. Two thread mappings:
//   MFMA:   wave w: g=w&3 (16-row group), h=w>>2 (512-code half); lane: col,quad
//   refine: row = t>>3 (0..63), q8 = t&7 (two 16-dim slices: q8*16 & 128+q8*16)
// Each thread holds xs[32] f32 of x for its (row, slices) — loaded ONCE at start.
// A fragments built via a transient XOR-swizzled bf16 LDS x-tile (aliases buf1).
// Candidate merge: sCd transposed [96][66] (conflict-free), parallel 8-thr/row
// exact top-8 selection via sorted-chunk + shfl-min rounds.
// enc + outq use PLAIN stores (complete at L2; HBM eviction drains async).
__global__ __launch_bounds__(512, 4) void gemm_topk_quant(
    const float* __restrict__ x, const unsigned short* __restrict__ Wb,
    const float* __restrict__ wnorm, const double* __restrict__ wnd,
    const float* __restrict__ Wm,
    float* __restrict__ enc_sum,
    float* __restrict__ enc,
    float* __restrict__ outq, float* __restrict__ loss_part)
{
    __shared__ __align__(16) char lds[65536];
    // post-loop aliases (all used only after the main loop's final barrier)
    float*  sCd   = (float*)lds;                 // [96][66] f32 = 25344 B (dies at merge)
    float*  qtile = (float*)lds;                 // [128][67] f32 = 34304 B (epilogue only)
    double* rd    = (double*)(lds + 34816);      // [512] f64 -> 38912
    double* rnr   = (double*)(lds + 38912);      // [64]  f64 -> 39424
    int*    s0    = (int*)(lds + 39424);         // [64] -> 39680
    int*    s1    = (int*)(lds + 39680);         // [64] -> 39936
    float*  sw0   = (float*)(lds + 39936);       // [64] -> 40192
    float*  sw1   = (float*)(lds + 40192);       // [64] -> 40448
    double* sredd = (double*)(lds + 40448);      // [8]  -> 40512
    int*    mIdx  = (int*)(lds + 40960);         // [512] -> 43008
    unsigned short* xtile = (unsigned short*)(lds + 32768);  // [64][256] bf16 swizzled, pre-loop only

    const int t    = threadIdx.x;
    const int wave = t >> 6;
    const int g    = wave & 3;
    const int h    = wave >> 2;
    const int lane = t & 63;
    const int col  = lane & 15;
    const int quad = lane >> 4;
    const int r0   = blockIdx.x * 64;
    const int b    = r0 >> 10;
    const int hw0  = r0 & 1023;
    const float* xblk = x + (size_t)b * 262144 + hw0;   // + d*1024 + hw_local

    const int row = t >> 3;   // refine/epilogue row (hw local)
    const int q8  = t & 7;    // dim-slice

    // ---- issue prologue B staging (buf0 @ lds[0..32K]) first ----
    const char* wb_bytes = (const char*)Wb;
    const size_t src_wave = (size_t)h * 262144 + (size_t)g * 4096;
    const int    lds_wave = h * 16384 + g * 4096;
    {
        const char* src = wb_bytes + src_wave;
        char* dstl = lds + lds_wave;
        #pragma unroll
        for (int q = 0; q < 4; ++q)
            gl_lds16(src + q * 1024 + lane * 16, dstl + q * 1024);
    }

    // ---- xs: this thread's 32 x values (row, dims p2*128 + q8*16 + j) ----
    float xs[32];
    {
        const float* xr = xblk + row;
        #pragma unroll
        for (int p2 = 0; p2 < 2; ++p2)
            #pragma unroll
            for (int j = 0; j < 16; ++j)
                xs[p2 * 16 + j] = xr[(size_t)(p2 * 128 + q8 * 16 + j) * 1024];
    }

    // ---- build bf16 x-tile [64][256] in LDS (upper 32K, aliases buf1) ----
    // XOR-swizzle short-index bit 3 with row&7 (16B unit) to spread banks.
    #pragma unroll
    for (int p2 = 0; p2 < 2; ++p2)
        #pragma unroll
        for (int j4 = 0; j4 < 4; ++j4) {
            ushort4 o;
            o.x = f2bf(xs[p2 * 16 + j4 * 4 + 0]);
            o.y = f2bf(xs[p2 * 16 + j4 * 4 + 1]);
            o.z = f2bf(xs[p2 * 16 + j4 * 4 + 2]);
            o.w = f2bf(xs[p2 * 16 + j4 * 4 + 3]);
            const int xi = (row * 256 + p2 * 128 + q8 * 16 + j4 * 4) ^ ((row & 7) << 3);
            *(ushort4*)(xtile + xi) = o;
        }
    __syncthreads();

    // ---- A fragments from x-tile (both halves read the same 16 rows) ----
    short8 af[8];
    #pragma unroll
    for (int kk = 0; kk < 8; ++kk) {
        const int xi = ((g * 16 + col) * 256 + kk * 32 + quad * 8) ^ ((col & 7) << 3);
        af[kk] = *(const short8*)(xtile + xi);
    }
    __syncthreads();   // af reads done; buf0 staged (vmcnt drained). cc=0 may now overwrite xtile.

    float m0[4], m1[4], m2[4];
    #pragma unroll
    for (int r = 0; r < 4; ++r) { m0[r] = 3.4e38f; m1[r] = 3.4e38f; m2[r] = 3.4e38f; }

    for (int cc = 0; cc < 16; ++cc) {
        if (cc < 15) {
            const char* src = wb_bytes + src_wave + (size_t)(cc + 1) * 16384;
            char* dstl = lds + ((cc + 1) & 1) * 32768 + lds_wave;
            #pragma unroll
            for (int q = 0; q < 4; ++q)
                gl_lds16(src + q * 1024 + lane * 16, dstl + q * 1024);
        }
        const char* bb = lds + (cc & 1) * 32768 + h * 16384;
        f32x4 acc0 = {0.f, 0.f, 0.f, 0.f};
        f32x4 acc1 = {0.f, 0.f, 0.f, 0.f};
        #pragma unroll
        for (int kk = 0; kk < 8; ++kk) {
            short8 b0 = *(const short8*)(bb + kk * 1024 + lane * 16);
            short8 b1 = *(const short8*)(bb + 8192 + kk * 1024 + lane * 16);
            acc0 = __builtin_amdgcn_mfma_f32_16x16x32_bf16(af[kk], b0, acc0, 0, 0, 0);
            acc1 = __builtin_amdgcn_mfma_f32_16x16x32_bf16(af[kk], b1, acc1, 0, 0, 0);
        }
        const int code0 = h * 512 + cc * 32 + col;
        const int code1 = code0 + 16;
        const float wn0 = wnorm[code0];
        const float wn1 = wnorm[code1];
        #pragma unroll
        for (int r = 0; r < 4; ++r) {
            float pv0 = packdi(fmaf(-2.0f, acc0[r], wn0), code0);
            float t0  = fmaxf(m0[r], pv0); m0[r] = fminf(m0[r], pv0);
            float t1  = fmaxf(m1[r], t0);  m1[r] = fminf(m1[r], t0);
            m2[r] = fminf(m2[r], t1);
            float pv1 = packdi(fmaf(-2.0f, acc1[r], wn1), code1);
            t0 = fmaxf(m0[r], pv1); m0[r] = fminf(m0[r], pv1);
            t1 = fmaxf(m1[r], t0);  m1[r] = fminf(m1[r], t0);
            m2[r] = fminf(m2[r], t1);
        }
        __syncthreads();   // staged data for cc+1 visible; buf[cc&1] reads done
    }

    // ---- dump per-lane candidates, transposed layout [96 slots][66 rows] ----
    #pragma unroll
    for (int r = 0; r < 4; ++r) {
        const int rl = g * 16 + quad * 4 + r;
        const int s  = h * 48 + col * 3;
        sCd[(s + 0) * 66 + rl] = m0[r];
        sCd[(s + 1) * 66 + rl] = m1[r];
        sCd[(s + 2) * 66 + rl] = m2[r];
    }
    __syncthreads();

    // ---- parallel exact top-8 merge: 8 threads/row, 12 slots each ----
    {
        float a0 = 3.4e38f, a1 = 3.4e38f, a2 = 3.4e38f, a3 = 3.4e38f,
              a4 = 3.4e38f, a5 = 3.4e38f, a6 = 3.4e38f, a7 = 3.4e38f;
        #pragma unroll
        for (int i = 0; i < 12; ++i) {
            float d = sCd[(q8 * 12 + i) * 66 + row];
            if (d < a7) {
                a7 = d; float tf;
                if (a7 < a6) { tf = a7; a7 = a6; a6 = tf; }
                if (a6 < a5) { tf = a6; a6 = a5; a5 = tf; }
                if (a5 < a4) { tf = a5; a5 = a4; a4 = tf; }
                if (a4 < a3) { tf = a4; a4 = a3; a3 = tf; }
                if (a3 < a2) { tf = a3; a3 = a2; a2 = tf; }
                if (a2 < a1) { tf = a2; a2 = a1; a1 = tf; }
                if (a1 < a0) { tf = a1; a1 = a0; a0 = tf; }
            }
        }
        // 8 rounds: global min of the 8 heads (values unique via packed code bits)
        float sel = 3.4e38f;
        #pragma unroll
        for (int q = 0; q < 8; ++q) {
            float m = a0;
            m = fminf(m, __shfl_xor(m, 1));
            m = fminf(m, __shfl_xor(m, 2));
            m = fminf(m, __shfl_xor(m, 4));
            if (q8 == q) sel = m;
            if (a0 == m) { a0 = a1; a1 = a2; a2 = a3; a3 = a4;
                           a4 = a5; a5 = a6; a6 = a7; a7 = 3.4e38f; }
        }
        mIdx[row * 8 + q8] = (int)(__float_as_uint(sel) & 1023u);
    }
    __syncthreads();

    // ---- fp64 refine from xs regs: partial dots per slice, shfl_xor reduce ----
    {
        int cd[8];
        #pragma unroll
        for (int c8 = 0; c8 < 8; ++c8) cd[c8] = mIdx[row * 8 + c8];
        double dot[8];
        #pragma unroll
        for (int c8 = 0; c8 < 8; ++c8) dot[c8] = 0.0;
        double rn = 0.0;
        #pragma unroll
        for (int v = 0; v < 8; ++v) {
            const int d0 = (v >> 2) * 128 + q8 * 16 + (v & 3) * 4;
            const double x0 = (double)xs[v * 4 + 0];
            const double x1 = (double)xs[v * 4 + 1];
            const double x2 = (double)xs[v * 4 + 2];
            const double x3 = (double)xs[v * 4 + 3];
            rn += x0*x0 + x1*x1 + x2*x2 + x3*x3;
            #pragma unroll
            for (int c8 = 0; c8 < 8; ++c8) {
                const float4 wv = *(const float4*)(Wm + (size_t)cd[c8] * 256 + d0);
                dot[c8] += x0 * (double)wv.x + x1 * (double)wv.y
                         + x2 * (double)wv.z + x3 * (double)wv.w;
            }
        }
        #pragma unroll
        for (int m = 1; m < 8; m <<= 1) {
            #pragma unroll
            for (int c8 = 0; c8 < 8; ++c8) dot[c8] += __shfl_xor(dot[c8], m);
            rn += __shfl_xor(rn, m);
        }
        // static select of this thread's candidate (avoid dynamic reg indexing)
        int myc = 0; double mydot = 0.0;
        #pragma unroll
        for (int c8 = 0; c8 < 8; ++c8)
            if (q8 == c8) { myc = cd[c8]; mydot = dot[c8]; }
        rd[row * 8 + q8] = wnd[myc] - 2.0 * mydot;
        if (q8 == 0) rnr[row] = rn;
    }
    __syncthreads();

    // ---- final per-row top-2 (exact), weights ----
    if (t < 64) {
        double rn = rnr[t];
        double d0 = 1e300, d1 = 1e300; int b0 = 1 << 30, b1 = 1 << 30;
        #pragma unroll
        for (int q = 0; q < 8; ++q) {
            double d = rd[t * 8 + q];
            int    c = mIdx[t * 8 + q];
            if (d < d0 || (d == d0 && c < b0)) { d1 = d0; b1 = b0; d0 = d; b0 = c; }
            else if (d < d1 || (d == d1 && c < b1)) { d1 = d; b1 = c; }
        }
        double D0 = rn + d0;
        double D1 = rn + d1;
        double inv0 = 1.0 / D0, inv1 = 1.0 / D1;
        double nrm = sqrt(inv0 * inv0 + inv1 * inv1);
        if (nrm < 1e-12) nrm = 1e-12;
        float w0 = (float)(inv0 / nrm);
        float w1 = (float)(inv1 / nrm);
        s0[t] = b0; s1[t] = b1; sw0[t] = w0; sw1[t] = w1;
        atomicAdd(&enc_sum[b0], w0);
        atomicAdd(&enc_sum[b1], w1);
    }
    __syncthreads();

    // ---- encodings rows: wave w writes rows w*8..w*8+7, coalesced stores ----
    // plain stores: complete at L2, HBM eviction drains asynchronously
    #pragma unroll
    for (int rr = 0; rr < 8; ++rr) {
        const int rw = wave * 8 + rr;
        const int i0 = s0[rw], i1 = s1[rw];
        const float w0 = sw0[rw], w1 = sw1[rw];
        f32x4* dst = (f32x4*)(enc + (size_t)(r0 + rw) * KCODES);
        #pragma unroll
        for (int it = 0; it < 4; ++it) {
            const int base = it * 256 + lane * 4;
            f32x4 v;
            v.x = (base + 0 == i0) ? w0 : ((base + 0 == i1) ? w1 : 0.0f);
            v.y = (base + 1 == i0) ? w0 : ((base + 1 == i1) ? w1 : 0.0f);
            v.z = (base + 2 == i0) ? w0 : ((base + 2 == i1) ? w1 : 0.0f);
            v.w = (base + 3 == i0) ? w0 : ((base + 3 == i1) ? w1 : 0.0f);
            dst[it * 64 + lane] = v;
        }
    }

    // ---- quantize + loss (from xs) + NCHW write, 2 chunks of 128 channels ----
    double ls = 0.0;
    #pragma unroll
    for (int p2 = 0; p2 < 2; ++p2) {
        const int   cA = s0[row], cB = s1[row];
        const float w0 = sw0[row], w1 = sw1[row];
        const float* W0 = Wm + (size_t)cA * 256 + p2 * 128 + q8 * 16;
        const float* W1 = Wm + (size_t)cB * 256 + p2 * 128 + q8 * 16;
        #pragma unroll
        for (int v4 = 0; v4 < 4; ++v4) {
            const float4 a  = *(const float4*)(W0 + v4 * 4);
            const float4 bv = *(const float4*)(W1 + v4 * 4);
            float q0 = w0 * a.x + w1 * bv.x;
            float q1 = w0 * a.y + w1 * bv.y;
            float q2 = w0 * a.z + w1 * bv.z;
            float q3 = w0 * a.w + w1 * bv.w;
            float e0 = q0 - xs[p2 * 16 + v4 * 4 + 0];
            float e1 = q1 - xs[p2 * 16 + v4 * 4 + 1];
            float e2 = q2 - xs[p2 * 16 + v4 * 4 + 2];
            float e3 = q3 - xs[p2 * 16 + v4 * 4 + 3];
            ls += (double)(e0*e0 + e1*e1 + e2*e2 + e3*e3);
            const int dl = q8 * 16 + v4 * 4;
            qtile[(dl + 0) * 67 + row] = q0;
            qtile[(dl + 1) * 67 + row] = q1;
            qtile[(dl + 2) * 67 + row] = q2;
            qtile[(dl + 3) * 67 + row] = q3;
        }
        __syncthreads();
        #pragma unroll
        for (int p = 0; p < 4; ++p) {
            const int task = p * 512 + t;
            const int cl   = task >> 4;       // channel-local 0..127
            const int hwq  = task & 15;
            f32x4 v;
            v.x = qtile[cl * 67 + hwq * 4 + 0];
            v.y = qtile[cl * 67 + hwq * 4 + 1];
            v.z = qtile[cl * 67 + hwq * 4 + 2];
            v.w = qtile[cl * 67 + hwq * 4 + 3];
            *(f32x4*)(outq + ((size_t)(b * 256 + p2 * 128 + cl)) * 1024 + hw0 + hwq * 4) = v;
        }
        __syncthreads();
    }

    // ---- block loss partial ----
    #pragma unroll
    for (int off = 32; off > 0; off >>= 1) ls += __shfl_down(ls, off);
    if (lane == 0) sredd[wave] = ls;
    __syncthreads();
    if (t == 0) {
        double s = 0.0;
        #pragma unroll
        for (int w = 0; w < 8; ++w) s += sredd[w];
        loss_part[blockIdx.x] = (float)s;
    }
}

// ---------------- finalize: loss + perplexity ----------------
__global__ __launch_bounds__(256) void finalize_k(const float* __restrict__ enc_sum,
                                                  const float* __restrict__ loss_part,
                                                  float* __restrict__ out)
{
    __shared__ double sh[256];
    const int t = threadIdx.x;
    double ls = 0.0;
    for (int i = t; i < 512; i += 256) ls += (double)loss_part[i];
    sh[t] = ls; __syncthreads();
    for (int s = 128; s > 0; s >>= 1) { if (t < s) sh[t] += sh[t + s]; __syncthreads(); }
    double loss_sum = sh[0];
    __syncthreads();
    double ps = 0.0;
    for (int k = t; k < KCODES; k += 256) {
        double p = (double)enc_sum[k] / (double)NROWS;
        ps += p * log(p + 1e-10);
    }
    sh[t] = ps; __syncthreads();
    for (int s = 128; s > 0; s >>= 1) { if (t < s) sh[t] += sh[t + s]; __syncthreads(); }
    if (t == 0) {
        out[0]        = (float)(1.25 * loss_sum / 8388608.0);
        out[OUT_PERP] = (float)exp(-sh[0]);
    }
}

extern "C" void kernel_launch(void* const* d_in, const int* in_sizes, int n_in,
                              void* d_out, int out_size, void* d_ws, size_t ws_size,
                              hipStream_t stream)
{
    const float* x  = (const float*)d_in[0];
    const float* Wm = (const float*)d_in[1];
    float* out = (float*)d_out;
    float* ws  = (float*)d_ws;

    unsigned short* Wb      = (unsigned short*)(ws + OFF_WB);
    float*          wnorm   = ws + OFF_WNORM;
    float*          enc_sum = ws + OFF_ENCSUM;
    float*          loss_p  = ws + OFF_LOSSP;
    double*         wnd     = (double*)(ws + OFF_WND);

    wprep<<<KCODES / 4, 256, 0, stream>>>(Wm, Wb, wnorm, wnd, enc_sum);
    gemm_topk_quant<<<NROWS / 64, 512, 0, stream>>>(x, Wb, wnorm, wnd, Wm, enc_sum,
                                                    out + OUT_ENC, out + OUT_Q, loss_p);
    finalize_k<<<1, 256, 0, stream>>>(enc_sum, loss_p, out);
}

// Round 5
// 260.957 us; speedup vs baseline: 1.2410x; 1.0084x over previous
//
#include <hip/hip_runtime.h>
#include <math.h>

// Problem constants (fixed by setup_inputs)
#define NROWS 32768   // 32 * 32 * 32
#define DIMS  256
#define KCODES 1024

typedef __attribute__((ext_vector_type(8))) short short8;   // 8 bf16 = 4 VGPRs
typedef __attribute__((ext_vector_type(4))) float f32x4;    // MFMA C/D & stores

// ws layout (float offsets)
static const size_t OFF_WB     = 8388608;                // [1024][256] bf16, MFMA-fragment tile order
static const size_t OFF_WNORM  = OFF_WB + 131072;        // [1024] f32
static const size_t OFF_ENCSUM = OFF_WNORM + 1024;       // [1024]
static const size_t OFF_LOSSP  = OFF_ENCSUM + 1024;      // [1024 used]
static const size_t OFF_WND    = OFF_LOSSP + 8192;       // [1024] f64 (2048 floats), 8B aligned

// out layout (float offsets): loss | quantized NCHW | perplexity | encodings
static const size_t OUT_Q    = 1;
static const size_t OUT_PERP = 8388609;
static const size_t OUT_ENC  = 8388610;

__device__ inline unsigned short f2bf(float f) {
    unsigned int u = __float_as_uint(f);
    unsigned int r = u + 0x7FFFu + ((u >> 16) & 1u);   // RNE
    return (unsigned short)(r >> 16);
}

// pack distance (fp32, low 10 mantissa bits cleared) with 10-bit code index.
__device__ inline float packdi(float d, int code) {
    return __uint_as_float((__float_as_uint(d) & 0xFFFFFC00u) | (unsigned)code);
}

// async global->LDS copy, 16B per lane (wave-uniform LDS base + lane*16)
__device__ __forceinline__ void gl_lds16(const void* gsrc, void* ldst) {
    typedef const __attribute__((address_space(1))) unsigned int GU;
    typedef __attribute__((address_space(3))) unsigned int LU;
    __builtin_amdgcn_global_load_lds((GU*)gsrc, (LU*)ldst, 16, 0, 0);
}

// ---------------- W prep: bf16 fragment-order layout + wnorm (f32+f64) ----
__global__ __launch_bounds__(256) void wprep(const float* __restrict__ Wm,
                                             unsigned short* __restrict__ Wb,
                                             float* __restrict__ wnorm,
                                             double* __restrict__ wnormd,
                                             float* __restrict__ enc_sum)
{
    const int r = blockIdx.x * 4 + (threadIdx.x >> 6);
    const int lane = threadIdx.x & 63;
    float4 v = ((const float4*)(Wm + (size_t)r * 256))[lane];
    ushort4 o;
    o.x = f2bf(v.x); o.y = f2bf(v.y); o.z = f2bf(v.z); o.w = f2bf(v.w);
    const int d0 = lane * 4;
    const int kk = d0 >> 5, quad = (d0 >> 3) & 3, jb = d0 & 7;
    const int tt = r >> 4, col = r & 15;
    const size_t idx = (size_t)tt * 4096 + (size_t)((kk * 4 + quad) * 16 + col) * 8 + jb;
    *(ushort4*)(Wb + idx) = o;
    double s = (double)v.x*(double)v.x + (double)v.y*(double)v.y
             + (double)v.z*(double)v.z + (double)v.w*(double)v.w;
    #pragma unroll
    for (int off = 32; off > 0; off >>= 1) s += __shfl_down(s, off);
    if (lane == 0) { wnormd[r] = s; wnorm[r] = (float)s; }
    if (blockIdx.x == 0) {
        #pragma unroll
        for (int q = 0; q < 4; ++q) enc_sum[threadIdx.x * 4 + q] = 0.0f;
    }
}

// ---------------- fused MFMA GEMM + top-k + fp64 refine + enc + quantize + loss ----
// 256 thr = 4 waves, 32 rows/block, grid 1024, LDS 32 KB -> 4 blocks/CU resident.
// Mappings:
//   MFMA:   wave w: g=w&1 (16-row group), h=w>>1 (512-code half); lane: col,quad
//   refine: row = t>>3 (0..31), q8 = t&7 (two 16-dim slices: q8*16 & 128+q8*16)
// Per cc (32 iters) each half processes one 16-code tile (8 KB); candidate pool
// per (row, col, h) = 3 minima over the same 32-code column set as before.
// B double-buffered 2x16KB staged via global_load_lds; A fragments from a
// transient XOR-swizzled bf16 LDS x-tile (aliases buf1).
// enc + outq use plain stores (complete at L2; HBM eviction drains async).
__global__ __launch_bounds__(256, 4) void gemm_topk_quant(
    const float* __restrict__ x, const unsigned short* __restrict__ Wb,
    const float* __restrict__ wnorm, const double* __restrict__ wnd,
    const float* __restrict__ Wm,
    float* __restrict__ enc_sum,
    float* __restrict__ enc,
    float* __restrict__ outq, float* __restrict__ loss_part)
{
    __shared__ __align__(16) char lds[32768];
    // loop: buf0 = lds[0,16K), buf1 = lds[16K,32K)
    // post-loop aliases (phases separated by barriers):
    float*  sCd   = (float*)lds;                 // [96][34] f32 = 13056 B (dump->merge)
    int*    mIdx  = (int*)(lds + 13312);         // [256] -> 14336
    double* rd    = (double*)(lds + 14336);      // [256] f64 -> 16384
    float*  qtile = (float*)lds;                 // [32][132] f32 = 16896 B (epilogue)
    double* rnr   = (double*)(lds + 16896);      // [32] f64 -> 17152
    int*    s0    = (int*)(lds + 17152);         // [32]
    int*    s1    = (int*)(lds + 17280);         // [32]
    float*  sw0   = (float*)(lds + 17408);       // [32]
    float*  sw1   = (float*)(lds + 17536);       // [32]
    double* sredd = (double*)(lds + 17664);      // [4]
    unsigned short* xtile = (unsigned short*)(lds + 16384);  // [32][256] bf16 swizzled, pre-loop

    const int t    = threadIdx.x;
    const int wave = t >> 6;
    const int g    = wave & 1;
    const int h    = wave >> 1;
    const int lane = t & 63;
    const int col  = lane & 15;
    const int quad = lane >> 4;
    const int r0   = blockIdx.x * 32;
    const int b    = r0 >> 10;
    const int hw0  = r0 & 1023;
    const float* xblk = x + (size_t)b * 262144 + hw0;   // + d*1024 + hw_local

    const int row = t >> 3;   // refine/epilogue row (hw local), 0..31
    const int q8  = t & 7;    // dim-slice

    // ---- issue prologue B staging (cc=0 tile -> buf0) first ----
    const char* wb_bytes = (const char*)Wb;
    {
        const char* src = wb_bytes + (size_t)(h * 32) * 8192 + g * 4096;
        char* dstl = lds + h * 8192 + g * 4096;
        #pragma unroll
        for (int q = 0; q < 4; ++q)
            gl_lds16(src + q * 1024 + lane * 16, dstl + q * 1024);
    }

    // ---- xs: this thread's 32 x values (row, dims p2*128 + q8*16 + j) ----
    float xs[32];
    {
        const float* xr = xblk + row;
        #pragma unroll
        for (int p2 = 0; p2 < 2; ++p2)
            #pragma unroll
            for (int j = 0; j < 16; ++j)
                xs[p2 * 16 + j] = xr[(size_t)(p2 * 128 + q8 * 16 + j) * 1024];
    }

    // ---- build bf16 x-tile [32][256] in LDS (upper 16K, aliases buf1) ----
    // XOR-swizzle short-index bits 3..5 with row&7 (16B unit) to spread banks.
    #pragma unroll
    for (int p2 = 0; p2 < 2; ++p2)
        #pragma unroll
        for (int j4 = 0; j4 < 4; ++j4) {
            ushort4 o;
            o.x = f2bf(xs[p2 * 16 + j4 * 4 + 0]);
            o.y = f2bf(xs[p2 * 16 + j4 * 4 + 1]);
            o.z = f2bf(xs[p2 * 16 + j4 * 4 + 2]);
            o.w = f2bf(xs[p2 * 16 + j4 * 4 + 3]);
            const int xi = (row * 256 + p2 * 128 + q8 * 16 + j4 * 4) ^ ((row & 7) << 3);
            *(ushort4*)(xtile + xi) = o;
        }
    __syncthreads();

    // ---- A fragments from x-tile (rows g*16..g*16+15) ----
    short8 af[8];
    #pragma unroll
    for (int kk = 0; kk < 8; ++kk) {
        const int xi = ((g * 16 + col) * 256 + kk * 32 + quad * 8) ^ ((col & 7) << 3);
        af[kk] = *(const short8*)(xtile + xi);
    }
    __syncthreads();   // af reads done; buf0 staged (vmcnt drained). cc=0 may overwrite xtile.

    float m0[4], m1[4], m2[4];
    #pragma unroll
    for (int r = 0; r < 4; ++r) { m0[r] = 3.4e38f; m1[r] = 3.4e38f; m2[r] = 3.4e38f; }

    for (int cc = 0; cc < 32; ++cc) {
        if (cc < 31) {
            const char* src = wb_bytes + (size_t)(h * 32 + cc + 1) * 8192 + g * 4096;
            char* dstl = lds + ((cc + 1) & 1) * 16384 + h * 8192 + g * 4096;
            #pragma unroll
            for (int q = 0; q < 4; ++q)
                gl_lds16(src + q * 1024 + lane * 16, dstl + q * 1024);
        }
        const char* bb = lds + (cc & 1) * 16384 + h * 8192;
        f32x4 acc = {0.f, 0.f, 0.f, 0.f};
        #pragma unroll
        for (int kk = 0; kk < 8; ++kk) {
            short8 b0 = *(const short8*)(bb + kk * 1024 + lane * 16);
            acc = __builtin_amdgcn_mfma_f32_16x16x32_bf16(af[kk], b0, acc, 0, 0, 0);
        }
        const int code0 = h * 512 + cc * 16 + col;
        const float wn0 = wnorm[code0];
        #pragma unroll
        for (int r = 0; r < 4; ++r) {
            float pv0 = packdi(fmaf(-2.0f, acc[r], wn0), code0);
            float t0  = fmaxf(m0[r], pv0); m0[r] = fminf(m0[r], pv0);
            float t1  = fmaxf(m1[r], t0);  m1[r] = fminf(m1[r], t0);
            m2[r] = fminf(m2[r], t1);
        }
        __syncthreads();   // staged data for cc+1 visible; buf[cc&1] reads done
    }

    // ---- dump per-lane candidates, transposed layout [96 slots][34 rows] ----
    #pragma unroll
    for (int r = 0; r < 4; ++r) {
        const int rl = g * 16 + quad * 4 + r;
        const int s  = h * 48 + col * 3;
        sCd[(s + 0) * 34 + rl] = m0[r];
        sCd[(s + 1) * 34 + rl] = m1[r];
        sCd[(s + 2) * 34 + rl] = m2[r];
    }
    __syncthreads();

    // ---- parallel exact top-8 merge: 8 threads/row, 12 slots each ----
    {
        float a0 = 3.4e38f, a1 = 3.4e38f, a2 = 3.4e38f, a3 = 3.4e38f,
              a4 = 3.4e38f, a5 = 3.4e38f, a6 = 3.4e38f, a7 = 3.4e38f;
        #pragma unroll
        for (int i = 0; i < 12; ++i) {
            float d = sCd[(q8 * 12 + i) * 34 + row];
            if (d < a7) {
                a7 = d; float tf;
                if (a7 < a6) { tf = a7; a7 = a6; a6 = tf; }
                if (a6 < a5) { tf = a6; a6 = a5; a5 = tf; }
                if (a5 < a4) { tf = a5; a5 = a4; a4 = tf; }
                if (a4 < a3) { tf = a4; a4 = a3; a3 = tf; }
                if (a3 < a2) { tf = a3; a3 = a2; a2 = tf; }
                if (a2 < a1) { tf = a2; a2 = a1; a1 = tf; }
                if (a1 < a0) { tf = a1; a1 = a0; a0 = tf; }
            }
        }
        // 8 rounds: global min of the 8 heads (values unique via packed code bits)
        float sel = 3.4e38f;
        #pragma unroll
        for (int q = 0; q < 8; ++q) {
            float m = a0;
            m = fminf(m, __shfl_xor(m, 1));
            m = fminf(m, __shfl_xor(m, 2));
            m = fminf(m, __shfl_xor(m, 4));
            if (q8 == q) sel = m;
            if (a0 == m) { a0 = a1; a1 = a2; a2 = a3; a3 = a4;
                           a4 = a5; a5 = a6; a6 = a7; a7 = 3.4e38f; }
        }
        mIdx[row * 8 + q8] = (int)(__float_as_uint(sel) & 1023u);
    }
    __syncthreads();

    // ---- fp64 refine from xs regs: partial dots per slice, shfl_xor reduce ----
    {
        int cd[8];
        #pragma unroll
        for (int c8 = 0; c8 < 8; ++c8) cd[c8] = mIdx[row * 8 + c8];
        double dot[8];
        #pragma unroll
        for (int c8 = 0; c8 < 8; ++c8) dot[c8] = 0.0;
        double rn = 0.0;
        #pragma unroll
        for (int v = 0; v < 8; ++v) {
            const int d0 = (v >> 2) * 128 + q8 * 16 + (v & 3) * 4;
            const double x0 = (double)xs[v * 4 + 0];
            const double x1 = (double)xs[v * 4 + 1];
            const double x2 = (double)xs[v * 4 + 2];
            const double x3 = (double)xs[v * 4 + 3];
            rn += x0*x0 + x1*x1 + x2*x2 + x3*x3;
            #pragma unroll
            for (int c8 = 0; c8 < 8; ++c8) {
                const float4 wv = *(const float4*)(Wm + (size_t)cd[c8] * 256 + d0);
                dot[c8] += x0 * (double)wv.x + x1 * (double)wv.y
                         + x2 * (double)wv.z + x3 * (double)wv.w;
            }
        }
        #pragma unroll
        for (int m = 1; m < 8; m <<= 1) {
            #pragma unroll
            for (int c8 = 0; c8 < 8; ++c8) dot[c8] += __shfl_xor(dot[c8], m);
            rn += __shfl_xor(rn, m);
        }
        // static select of this thread's candidate (avoid dynamic reg indexing)
        int myc = 0; double mydot = 0.0;
        #pragma unroll
        for (int c8 = 0; c8 < 8; ++c8)
            if (q8 == c8) { myc = cd[c8]; mydot = dot[c8]; }
        rd[row * 8 + q8] = wnd[myc] - 2.0 * mydot;
        if (q8 == 0) rnr[row] = rn;
    }
    __syncthreads();

    // ---- final per-row top-2 (exact), weights ----
    if (t < 32) {
        double rn = rnr[t];
        double d0 = 1e300, d1 = 1e300; int b0 = 1 << 30, b1 = 1 << 30;
        #pragma unroll
        for (int q = 0; q < 8; ++q) {
            double d = rd[t * 8 + q];
            int    c = mIdx[t * 8 + q];
            if (d < d0 || (d == d0 && c < b0)) { d1 = d0; b1 = b0; d0 = d; b0 = c; }
            else if (d < d1 || (d == d1 && c < b1)) { d1 = d; b1 = c; }
        }
        double D0 = rn + d0;
        double D1 = rn + d1;
        double inv0 = 1.0 / D0, inv1 = 1.0 / D1;
        double nrm = sqrt(inv0 * inv0 + inv1 * inv1);
        if (nrm < 1e-12) nrm = 1e-12;
        float w0 = (float)(inv0 / nrm);
        float w1 = (float)(inv1 / nrm);
        s0[t] = b0; s1[t] = b1; sw0[t] = w0; sw1[t] = w1;
        atomicAdd(&enc_sum[b0], w0);
        atomicAdd(&enc_sum[b1], w1);
    }
    __syncthreads();

    // ---- encodings rows: wave w writes rows w*8..w*8+7, coalesced stores ----
    // plain stores: complete at L2, HBM eviction drains asynchronously
    #pragma unroll
    for (int rr = 0; rr < 8; ++rr) {
        const int rw = wave * 8 + rr;
        const int i0 = s0[rw], i1 = s1[rw];
        const float w0 = sw0[rw], w1 = sw1[rw];
        f32x4* dst = (f32x4*)(enc + (size_t)(r0 + rw) * KCODES);
        #pragma unroll
        for (int it = 0; it < 4; ++it) {
            const int base = it * 256 + lane * 4;
            f32x4 v;
            v.x = (base + 0 == i0) ? w0 : ((base + 0 == i1) ? w1 : 0.0f);
            v.y = (base + 1 == i0) ? w0 : ((base + 1 == i1) ? w1 : 0.0f);
            v.z = (base + 2 == i0) ? w0 : ((base + 2 == i1) ? w1 : 0.0f);
            v.w = (base + 3 == i0) ? w0 : ((base + 3 == i1) ? w1 : 0.0f);
            dst[it * 64 + lane] = v;
        }
    }

    // ---- quantize + loss (from xs) + NCHW write, 2 chunks of 128 channels ----
    double ls = 0.0;
    #pragma unroll
    for (int p2 = 0; p2 < 2; ++p2) {
        const int   cA = s0[row], cB = s1[row];
        const float w0 = sw0[row], w1 = sw1[row];
        const float* W0 = Wm + (size_t)cA * 256 + p2 * 128 + q8 * 16;
        const float* W1 = Wm + (size_t)cB * 256 + p2 * 128 + q8 * 16;
        #pragma unroll
        for (int v4 = 0; v4 < 4; ++v4) {
            const float4 a  = *(const float4*)(W0 + v4 * 4);
            const float4 bv = *(const float4*)(W1 + v4 * 4);
            f32x4 qv;
            qv.x = w0 * a.x + w1 * bv.x;
            qv.y = w0 * a.y + w1 * bv.y;
            qv.z = w0 * a.z + w1 * bv.z;
            qv.w = w0 * a.w + w1 * bv.w;
            float e0 = qv.x - xs[p2 * 16 + v4 * 4 + 0];
            float e1 = qv.y - xs[p2 * 16 + v4 * 4 + 1];
            float e2 = qv.z - xs[p2 * 16 + v4 * 4 + 2];
            float e3 = qv.w - xs[p2 * 16 + v4 * 4 + 3];
            ls += (double)(e0*e0 + e1*e1 + e2*e2 + e3*e3);
            const int dl = q8 * 16 + v4 * 4;
            *(f32x4*)(qtile + row * 132 + dl) = qv;
        }
        __syncthreads();
        #pragma unroll
        for (int p = 0; p < 4; ++p) {
            const int task = p * 256 + t;
            const int cl   = task >> 3;       // channel-local 0..127
            const int hwq  = task & 7;
            f32x4 v;
            v.x = qtile[(hwq * 4 + 0) * 132 + cl];
            v.y = qtile[(hwq * 4 + 1) * 132 + cl];
            v.z = qtile[(hwq * 4 + 2) * 132 + cl];
            v.w = qtile[(hwq * 4 + 3) * 132 + cl];
            *(f32x4*)(outq + ((size_t)(b * 256 + p2 * 128 + cl)) * 1024 + hw0 + hwq * 4) = v;
        }
        __syncthreads();
    }

    // ---- block loss partial ----
    #pragma unroll
    for (int off = 32; off > 0; off >>= 1) ls += __shfl_down(ls, off);
    if (lane == 0) sredd[wave] = ls;
    __syncthreads();
    if (t == 0) {
        double s = 0.0;
        #pragma unroll
        for (int w = 0; w < 4; ++w) s += sredd[w];
        loss_part[blockIdx.x] = (float)s;
    }
}

// ---------------- finalize: loss + perplexity ----------------
__global__ __launch_bounds__(256) void finalize_k(const float* __restrict__ enc_sum,
                                                  const float* __restrict__ loss_part,
                                                  float* __restrict__ out)
{
    __shared__ double sh[256];
    const int t = threadIdx.x;
    double ls = 0.0;
    for (int i = t; i < 1024; i += 256) ls += (double)loss_part[i];
    sh[t] = ls; __syncthreads();
    for (int s = 128; s > 0; s >>= 1) { if (t < s) sh[t] += sh[t + s]; __syncthreads(); }
    double loss_sum = sh[0];
    __syncthreads();
    double ps = 0.0;
    for (int k = t; k < KCODES; k += 256) {
        double p = (double)enc_sum[k] / (double)NROWS;
        ps += p * log(p + 1e-10);
    }
    sh[t] = ps; __syncthreads();
    for (int s = 128; s > 0; s >>= 1) { if (t < s) sh[t] += sh[t + s]; __syncthreads(); }
    if (t == 0) {
        out[0]        = (float)(1.25 * loss_sum / 8388608.0);
        out[OUT_PERP] = (float)exp(-sh[0]);
    }
}

extern "C" void kernel_launch(void* const* d_in, const int* in_sizes, int n_in,
                              void* d_out, int out_size, void* d_ws, size_t ws_size,
                              hipStream_t stream)
{
    const float* x  = (const float*)d_in[0];
    const float* Wm = (const float*)d_in[1];
    float* out = (float*)d_out;
    float* ws  = (float*)d_ws;

    unsigned short* Wb      = (unsigned short*)(ws + OFF_WB);
    float*          wnorm   = ws + OFF_WNORM;
    float*          enc_sum = ws + OFF_ENCSUM;
    float*          loss_p  = ws + OFF_LOSSP;
    double*         wnd     = (double*)(ws + OFF_WND);

    wprep<<<KCODES / 4, 256, 0, stream>>>(Wm, Wb, wnorm, wnd, enc_sum);
    gemm_topk_quant<<<NROWS / 32, 256, 0, stream>>>(x, Wb, wnorm, wnd, Wm, enc_sum,
                                                    out + OUT_ENC, out + OUT_Q, loss_p);
    finalize_k<<<1, 256, 0, stream>>>(enc_sum, loss_p, out);
}